// Round 13
// baseline (385.165 us; speedup 1.0000x reference)
//
#include <hip/hip_runtime.h>
#include <hip/hip_bf16.h>

#define B_ 2
#define S_ 2048
#define D_ 1024
#define H_ 16
#define DH_ 64
#define FF_ 4096
#define MTOK 4096  // B_*S_

using bf16 = __hip_bfloat16;
typedef short s16x8 __attribute__((ext_vector_type(8)));
typedef float f32x4 __attribute__((ext_vector_type(4)));
typedef float f32x16 __attribute__((ext_vector_type(16)));

#define MFMA_BF16(A, Bv, C) __builtin_amdgcn_mfma_f32_16x16x32_bf16(A, Bv, C, 0, 0, 0)
#define MFMA32(A, Bv, C) __builtin_amdgcn_mfma_f32_32x32x16_bf16(A, Bv, C, 0, 0, 0)

__device__ __forceinline__ void load_lds16(const void* g, void* l) {
  __builtin_amdgcn_global_load_lds(
      (const __attribute__((address_space(1))) void*)g,
      (__attribute__((address_space(3))) void*)l, 16, 0, 0);
}

__device__ __forceinline__ float bfr2f(unsigned short u) {
  return __uint_as_float(((unsigned)u) << 16);
}
__device__ __forceinline__ unsigned short f2bfr(float f) {
  __hip_bfloat16 h = __float2bfloat16(f);
  return *(unsigned short*)&h;
}
__device__ __forceinline__ unsigned cvtpk_bf16(float a, float b) {
  unsigned r;
  asm("v_cvt_pk_bf16_f32 %0, %1, %2" : "=v"(r) : "v"(a), "v"(b));
  return r;
}
__device__ __forceinline__ void pl32swap(unsigned& a, unsigned& b) {
  asm("v_permlane32_swap_b32 %0, %1" : "+v"(a), "+v"(b));
}

// ---------------------------------------------------------------------------
// Inputs are float32 (established r5->r6); sniffer kept as insurance.
// ---------------------------------------------------------------------------
__device__ int sniff_is_bf16(const unsigned* Xw) {
  int cnt = 0;
  for (int i = 0; i < 64; i++) {
    unsigned w = Xw[i];
    unsigned short h0 = (unsigned short)(w & 0xFFFF);
    unsigned short h1 = (unsigned short)(w >> 16);
    int e0 = (h0 >> 7) & 0xFF, e1 = (h1 >> 7) & 0xFF;
    if ((e0 >= 100 && e0 <= 140) || (h0 & 0x7FFF) == 0) cnt++;
    if ((e1 >= 100 && e1 <= 140) || (h1 & 0x7FFF) == 0) cnt++;
  }
  return cnt >= 110;
}

__device__ __forceinline__ void conv4(const void* src, bf16* dst, int i, int isbf) {
  ushort4 o;
  if (isbf) {
    o = *(const ushort4*)((const unsigned short*)src + i);
  } else {
    const float4 f = *(const float4*)((const float*)src + i);
    o.x = f2bfr(f.x); o.y = f2bfr(f.y); o.z = f2bfr(f.z); o.w = f2bfr(f.w);
  }
  *(ushort4*)((unsigned short*)dst + i) = o;
}

__global__ __launch_bounds__(256) void convert_kernel(
    const void* __restrict__ src, const unsigned* __restrict__ Xs,
    bf16* __restrict__ dst, int n) {
  __shared__ int isbf;
  if (threadIdx.x == 0) isbf = sniff_is_bf16(Xs);
  __syncthreads();
  int i = (blockIdx.x * 256 + threadIdx.x) * 4;
  if (i >= n) return;
  conv4(src, dst, i, isbf);
}

// three 1M-element weight tensors -> contiguous Wqkv
__global__ __launch_bounds__(256) void convert3_kernel(
    const void* __restrict__ s0, const void* __restrict__ s1,
    const void* __restrict__ s2, const unsigned* __restrict__ Xs,
    bf16* __restrict__ dst) {
  __shared__ int isbf;
  if (threadIdx.x == 0) isbf = sniff_is_bf16(Xs);
  __syncthreads();
  int i = (blockIdx.x * 256 + threadIdx.x) * 4;  // < 3*1048576
  int seg = i >> 20, loc = i & 1048575;
  const void* src = seg == 0 ? s0 : (seg == 1 ? s1 : s2);
  ushort4 o;
  if (isbf) {
    o = *(const ushort4*)((const unsigned short*)src + loc);
  } else {
    const float4 f = *(const float4*)((const float*)src + loc);
    o.x = f2bfr(f.x); o.y = f2bfr(f.y); o.z = f2bfr(f.z); o.w = f2bfr(f.w);
  }
  *(ushort4*)((unsigned short*)dst + i) = o;
}

// six small vectors -> contiguous block [ln1g|ln1b|ln2g|ln2b|b1|b2]
__global__ __launch_bounds__(256) void convertvec_kernel(
    const void* __restrict__ v0, const void* __restrict__ v1,
    const void* __restrict__ v2, const void* __restrict__ v3,
    const void* __restrict__ v4, const void* __restrict__ v5,
    const unsigned* __restrict__ Xs, bf16* __restrict__ dst) {
  __shared__ int isbf;
  if (threadIdx.x == 0) isbf = sniff_is_bf16(Xs);
  __syncthreads();
  int i = (blockIdx.x * 256 + threadIdx.x) * 4;  // < 9216
  if (i >= 9216) return;
  const void* src; int loc;
  if (i < 4096)      { int s = i >> 10; src = s == 0 ? v0 : s == 1 ? v1 : s == 2 ? v2 : v3; loc = i & 1023; }
  else if (i < 8192) { src = v4; loc = i - 4096; }
  else               { src = v5; loc = i - 8192; }
  ushort4 o;
  if (isbf) {
    o = *(const ushort4*)((const unsigned short*)src + loc);
  } else {
    const float4 f = *(const float4*)((const float*)src + loc);
    o.x = f2bfr(f.x); o.y = f2bfr(f.y); o.z = f2bfr(f.z); o.w = f2bfr(f.w);
  }
  *(ushort4*)((unsigned short*)dst + i) = o;
}

// ---------------------------------------------------------------------------
// 256x256-tile B^T GEMM, 512 threads (8 waves as 2M x 4N), BK=64, double-
// buffered LDS (128 KiB), 4-phase interleave per K-tile with counted vmcnt
// (T3+T4), LDS XOR-swizzle via pre-swizzled global source (rule #21),
// setprio around MFMA clusters (T5). Epilogue fully unrolled (rule #20).
// modes: 3 = relu(acc + bias)   (FFN1)
//        5 = fused QKV: N=3072; hx=gn>>6: <16 Q, <32 K, else V — head-major.
//            Q outputs are pre-scaled by 0.125 (exact bf16 exponent shift) so
//            attn skips the per-element score scale — bit-identical QK^T/8.
// ---------------------------------------------------------------------------
__global__ __launch_bounds__(512, 2) void gemm256(
    const bf16* __restrict__ A, const bf16* __restrict__ Bw,
    bf16* __restrict__ out, const bf16* __restrict__ bias,
    bf16* __restrict__ aux1, bf16* __restrict__ aux2,
    int M, int N, int K, int mode) {
  (void)M;
  __shared__ alignas(16) unsigned short As[4 * 256 * 32];  // [buf][khalf][256][32]
  __shared__ alignas(16) unsigned short Bs[4 * 256 * 32];
  const int tid = threadIdx.x;
  const int wave = tid >> 6, lane = tid & 63;
  const int col = lane & 15, quad = lane >> 4;
  const int wm = (wave >> 2) * 128, wn = (wave & 3) * 64;

  // bijective XCD-chunk swizzle (m204)
  const int gx = gridDim.x;
  const int nwg = gx * gridDim.y;
  const int orig = blockIdx.y * gx + blockIdx.x;
  const int qq = nwg >> 3, rr = nwg & 7;
  const int xcd = orig & 7, lid = orig >> 3;
  const int wg = (xcd < rr ? xcd * (qq + 1) : rr * (qq + 1) + (xcd - rr) * qq) + lid;
  const int m0 = (wg / gx) * 256, n0 = (wg % gx) * 256;

  // staging: per load, 64 lanes x 16B = 16 rows x 64B (one k-half row).
  // LDS dest is linear; source column pre-swizzled so read-side XOR works.
  const int srow = wave * 32 + (lane >> 2);
  const int scol = ((lane & 3) ^ ((lane >> 3) & 3)) * 16;  // bytes, within 64B row
  const char* ga = (const char*)A + (size_t)(m0 + srow) * (K * 2) + scol;
  const char* gb = (const char*)Bw + (size_t)(n0 + srow) * (K * 2) + scol;
  const int ldsw = wave * 1024;  // shorts; + i*512

#define STG_A(i, ks, ob, kb)                                                   \
  load_lds16(ga + (size_t)((i) * 16) * (K * 2) + (size_t)(kb) * 2 + (ks) * 64, \
             (void*)(As + ((((ob) * 2 + (ks)) << 13) + ldsw + (i) * 512)))
#define STG_B(i, ks, ob, kb)                                                   \
  load_lds16(gb + (size_t)((i) * 16) * (K * 2) + (size_t)(kb) * 2 + (ks) * 64, \
             (void*)(Bs + ((((ob) * 2 + (ks)) << 13) + ldsw + (i) * 512)))

  // fragment read addressing (swizzled): row r, phys slot = quad ^ ((r>>1)&3)
  const int swz8 = (quad ^ ((col >> 1) & 3)) * 8;  // shorts
  const int aoff = (wm + col) * 32 + swz8;
  const int boff = (wn + col) * 32 + swz8;

  const f32x4 fz = {0.f, 0.f, 0.f, 0.f};
  f32x4 acc[8][4];
#pragma unroll
  for (int i = 0; i < 8; i++)
#pragma unroll
    for (int j = 0; j < 4; j++) acc[i][j] = fz;

  s16x8 af[4], bfv[4];
#define LDA(ks, buf, mh)                                                       \
  _Pragma("unroll") for (int mt = 0; mt < 4; mt++)                             \
      af[mt] = *(const s16x8*)&As[((((buf) * 2 + (ks)) << 13) + aoff +         \
                                   ((mh) * 4 + mt) * 512)];
#define LDB(ks, buf)                                                           \
  _Pragma("unroll") for (int nt = 0; nt < 4; nt++)                             \
      bfv[nt] =                                                                \
          *(const s16x8*)&Bs[((((buf) * 2 + (ks)) << 13) + boff + nt * 512)];
#define MM(mh)                                                                 \
  __builtin_amdgcn_s_setprio(1);                                               \
  _Pragma("unroll") for (int mt = 0; mt < 4; mt++)                             \
      _Pragma("unroll") for (int nt = 0; nt < 4; nt++)                         \
          acc[(mh) * 4 + mt][nt] =                                             \
              MFMA_BF16(af[mt], bfv[nt], acc[(mh) * 4 + mt][nt]);              \
  __builtin_amdgcn_s_setprio(0);

  const int NT = K >> 6;
  // prologue: tile 0 -> buf 0, order Ak0,Bk0,Ak1,Bk1
  STG_A(0, 0, 0, 0); STG_A(1, 0, 0, 0);
  STG_B(0, 0, 0, 0); STG_B(1, 0, 0, 0);
  STG_A(0, 1, 0, 0); STG_A(1, 1, 0, 0);
  STG_B(0, 1, 0, 0); STG_B(1, 1, 0, 0);

  for (int t = 0; t < NT - 1; ++t) {
    const int buf = t & 1, ob = buf ^ 1;
    const int kb = (t + 1) << 6;
    __builtin_amdgcn_s_barrier();  // all waves done reading ob's old contents
    STG_A(0, 0, ob, kb); STG_A(1, 0, ob, kb);
    STG_B(0, 0, ob, kb); STG_B(1, 0, ob, kb);
    asm volatile("s_waitcnt vmcnt(6)" ::: "memory");  // Ak0,Bk0,Ak1 of tile t done
    __builtin_amdgcn_s_barrier();
    LDA(0, buf, 0); LDB(0, buf);
    MM(0);
    STG_A(0, 1, ob, kb); STG_A(1, 1, ob, kb);
    LDA(0, buf, 1);
    MM(1);
    STG_B(0, 1, ob, kb); STG_B(1, 1, ob, kb);
    asm volatile("s_waitcnt vmcnt(8)" ::: "memory");  // Bk1 of tile t done
    __builtin_amdgcn_s_barrier();
    LDA(1, buf, 0); LDB(1, buf);
    MM(0);
    LDA(1, buf, 1);
    MM(1);
  }
  {  // tail tile (no prefetch): single full drain
    const int buf = (NT - 1) & 1;
    __builtin_amdgcn_s_barrier();
    asm volatile("s_waitcnt vmcnt(0)" ::: "memory");
    __builtin_amdgcn_s_barrier();
    LDA(0, buf, 0); LDB(0, buf);
    MM(0);
    LDA(0, buf, 1);
    MM(1);
    LDA(1, buf, 0); LDB(1, buf);
    MM(0);
    LDA(1, buf, 1);
    MM(1);
  }
#undef STG_A
#undef STG_B
#undef LDA
#undef LDB
#undef MM

  // Fully-unrolled epilogue, mode branch hoisted (rule #20: no runtime
  // indexing into acc — keeps the accumulator in VGPRs).
  if (mode == 5) {
#pragma unroll
    for (int mt = 0; mt < 8; mt++)
#pragma unroll
      for (int nt = 0; nt < 4; nt++)
#pragma unroll
        for (int r = 0; r < 4; r++) {
          int gm = m0 + wm + mt * 16 + quad * 4 + r;
          int gn = n0 + wn + nt * 16 + col;
          int b = gm >> 11, s = gm & 2047, hx = gn >> 6, dh = gn & 63;
          bf16* dst = hx < 16 ? out : (hx < 32 ? aux1 : aux2);
          int h = hx & 15;
          float v = acc[mt][nt][r];
          if (hx < 16) v *= 0.125f;  // pre-scale Q (exact; attn skips the mul)
          dst[(((size_t)(b * H_ + h) * S_ + s) << 6) + dh] = __float2bfloat16(v);
        }
  } else {  // mode 3
#pragma unroll
    for (int mt = 0; mt < 8; mt++)
#pragma unroll
      for (int nt = 0; nt < 4; nt++)
#pragma unroll
        for (int r = 0; r < 4; r++) {
          int gm = m0 + wm + mt * 16 + quad * 4 + r;
          int gn = n0 + wn + nt * 16 + col;
          size_t idx = (size_t)gm * N + gn;
          float v = acc[mt][nt][r] + __bfloat162float(bias[gn]);
          out[idx] = __float2bfloat16(fmaxf(v, 0.f));
        }
  }
}

// ---------------------------------------------------------------------------
// 128x64-tile B^T GEMM, 256 threads (4 waves as 2M x 2N -> 64x32 per wave),
// BK=64, double-buffered LDS (48 KiB) -> THREE blocks co-resident per CU
// (144 KiB LDS, launch_bounds(256,3), VGPR 88 < 170 cap). r12 lesson: the
// r8 triple-buffer was neutral (stall is not load-landing latency) but its
// +24KB LDS capped occupancy at 2 blocks/CU; trading the dead buffer for a
// third independent barrier domain extends the r6->r7 win (+TLP to hide the
// LDS-read + barrier critical path). Depth-1 counted vmcnt(6) (r7 struct).
// XOR-swizzle via pre-swizzled global source (rule #21), unrolled epilogue.
// modes: 2 = acc + res (out-proj);  4 = acc + bias + res (FFN2)
// ---------------------------------------------------------------------------
__global__ __launch_bounds__(256, 3) void gemm64d(
    const bf16* __restrict__ A, const bf16* __restrict__ Bw,
    bf16* __restrict__ out, const bf16* __restrict__ bias,
    const bf16* __restrict__ res, int M, int N, int K, int mode) {
  (void)M;
  __shared__ alignas(16) unsigned short As[2 * 128 * 64];  // [buf][128][64]
  __shared__ alignas(16) unsigned short Bs[2 * 64 * 64];   // [buf][64][64]
  const int tid = threadIdx.x;
  const int wave = tid >> 6, lane = tid & 63;
  const int col = lane & 15, quad = lane >> 4;
  const int wm = (wave >> 1) * 64, wn = (wave & 1) * 32;
  const int sx = col & 7;  // read-side swizzle key

  // bijective XCD swizzle (nwg = 512, divisible by 8)
  const int gx = gridDim.x;  // 16
  const int orig = blockIdx.y * gx + blockIdx.x;
  const int nwg = gx * gridDim.y;
  const int wg = (orig & 7) * (nwg >> 3) + (orig >> 3);
  const int m0 = (wg / gx) * 128, n0 = (wg % gx) * 64;

  const int srow = tid >> 3;            // 0..31
  const int sslot = tid & 7;            // 16B slot
  const size_t K2 = (size_t)K * 2;      // row stride bytes
  const char* ga = (const char*)A + (size_t)(m0 + srow) * K2 +
                   ((sslot ^ (srow & 7)) << 4);
  const char* gb = (const char*)Bw + (size_t)(n0 + srow) * K2 +
                   ((sslot ^ (srow & 7)) << 4);

#define STG64(buf, kb)                                                         \
  {                                                                            \
    const size_t ko = (size_t)(kb) * 2;                                        \
    unsigned short* Ab = As + (buf) * 8192;                                    \
    unsigned short* Bb = Bs + (buf) * 4096;                                    \
    load_lds16(ga + ko,           (void*)(Ab + 0 * 2048 + wave * 512));        \
    load_lds16(ga + ko + 32 * K2, (void*)(Ab + 1 * 2048 + wave * 512));        \
    load_lds16(ga + ko + 64 * K2, (void*)(Ab + 2 * 2048 + wave * 512));        \
    load_lds16(ga + ko + 96 * K2, (void*)(Ab + 3 * 2048 + wave * 512));        \
    load_lds16(gb + ko,           (void*)(Bb + 0 * 2048 + wave * 512));        \
    load_lds16(gb + ko + 32 * K2, (void*)(Bb + 1 * 2048 + wave * 512));        \
  }

  const f32x4 fz = {0.f, 0.f, 0.f, 0.f};
  f32x4 acc[4][2];
#pragma unroll
  for (int i = 0; i < 4; i++)
#pragma unroll
    for (int j = 0; j < 2; j++) acc[i][j] = fz;

#define CMP64(buf)                                                             \
  _Pragma("unroll") for (int kh = 0; kh < 2; kh++) {                           \
    s16x8 Af[4], Bf[2];                                                        \
    const int so = ((kh * 4 + quad) ^ sx) * 8;                                 \
    _Pragma("unroll") for (int mt = 0; mt < 4; mt++)                           \
        Af[mt] = *(const s16x8*)&As[(buf) * 8192 + (wm + mt * 16 + col) * 64 + so]; \
    _Pragma("unroll") for (int nt = 0; nt < 2; nt++)                           \
        Bf[nt] = *(const s16x8*)&Bs[(buf) * 4096 + (wn + nt * 16 + col) * 64 + so]; \
    __builtin_amdgcn_s_setprio(1);                                             \
    _Pragma("unroll") for (int mt = 0; mt < 4; mt++)                           \
        _Pragma("unroll") for (int nt = 0; nt < 2; nt++)                       \
            acc[mt][nt] = MFMA_BF16(Af[mt], Bf[nt], acc[mt][nt]);              \
    __builtin_amdgcn_s_setprio(0);                                             \
  }

  const int NT = K >> 6;
  STG64(0, 0);
  for (int t = 0; t < NT - 1; ++t) {
    const int buf = t & 1;
    STG64(buf ^ 1, (t + 1) << 6);                     // prefetch next tile
    asm volatile("s_waitcnt vmcnt(6)" ::: "memory");  // tile t landed
    __builtin_amdgcn_s_barrier();
    CMP64(buf);
    __builtin_amdgcn_s_barrier();  // all waves done before buf reuse
  }
  {  // tail
    const int buf = (NT - 1) & 1;
    asm volatile("s_waitcnt vmcnt(0)" ::: "memory");
    __builtin_amdgcn_s_barrier();
    CMP64(buf);
  }
#undef STG64
#undef CMP64

  // Fully-unrolled epilogue, mode branch hoisted (rule #20).
  if (mode == 2) {
#pragma unroll
    for (int mt = 0; mt < 4; mt++)
#pragma unroll
      for (int nt = 0; nt < 2; nt++)
#pragma unroll
        for (int r = 0; r < 4; r++) {
          int gm = m0 + wm + mt * 16 + quad * 4 + r;
          int gn = n0 + wn + nt * 16 + col;
          size_t idx = (size_t)gm * N + gn;
          float v = acc[mt][nt][r] + __bfloat162float(res[idx]);
          out[idx] = __float2bfloat16(v);
        }
  } else {  // mode 4
#pragma unroll
    for (int mt = 0; mt < 4; mt++)
#pragma unroll
      for (int nt = 0; nt < 2; nt++)
#pragma unroll
        for (int r = 0; r < 4; r++) {
          int gm = m0 + wm + mt * 16 + quad * 4 + r;
          int gn = n0 + wn + nt * 16 + col;
          size_t idx = (size_t)gm * N + gn;
          float v = acc[mt][nt][r] + __bfloat162float(bias[gn]) +
                    __bfloat162float(res[idx]);
          out[idx] = __float2bfloat16(v);
        }
  }
}

// ---------------------------------------------------------------------------
// V head-major -> Vt [B,H,DH,S] transpose, 64x64 LDS tiles, coalesced I/O.
// ---------------------------------------------------------------------------
__global__ __launch_bounds__(256) void tpose_v(
    const bf16* __restrict__ Vb, bf16* __restrict__ Vt) {
  __shared__ unsigned short Ts[64][72];
  const int tid = threadIdx.x;
  const int bh = blockIdx.y, kt = blockIdx.x;
  const unsigned short* in =
      (const unsigned short*)Vb + (((size_t)bh * S_ + kt * 64) << 6);
  unsigned short* outp =
      (unsigned short*)Vt + ((size_t)bh << 17) + kt * 64;

  const int r = tid >> 2, cc = (tid & 3) * 16;
  s16x8 a = *(const s16x8*)(in + r * 64 + cc);
  s16x8 b = *(const s16x8*)(in + r * 64 + cc + 8);
  for (int j = 0; j < 8; j++) Ts[cc + j][r] = (unsigned short)a[j];
  for (int j = 0; j < 8; j++) Ts[cc + 8 + j][r] = (unsigned short)b[j];
  __syncthreads();
  const int dh = tid >> 2, sc = (tid & 3) * 16;
  s16x8 o0, o1;
  for (int j = 0; j < 8; j++) o0[j] = (short)Ts[dh][sc + j];
  for (int j = 0; j < 8; j++) o1[j] = (short)Ts[dh][sc + 8 + j];
  *(s16x8*)(outp + (size_t)dh * S_ + sc) = o0;
  *(s16x8*)(outp + (size_t)dh * S_ + sc + 8) = o1;
}

// ---------------------------------------------------------------------------
// Flash attention, 32x32x16 MFMA, swapped QK^T (P stays in registers).
// 4 waves x 32 q-rows = 128 q-rows per block; grid (S/128, B*H).
// T15 two-tile pipeline: tile t's QK^T (LDS-gated MFMA) overlaps tile t-1's
// exp+cvt+PV (register-only VALU+MFMA). Two named P/V register sets (A/B,
// rule #20). PV executes tiles in order -> accumulation order bit-identical.
// Q arrives pre-scaled by 0.125 (gemm256 mode-5); __expf fast path (r10).
// ---------------------------------------------------------------------------
__global__ __launch_bounds__(256, 2) void attn_kernel(
    const bf16* __restrict__ Q, const bf16* __restrict__ Kb,
    const bf16* __restrict__ Vt, bf16* __restrict__ ctx) {
  __shared__ alignas(16) unsigned short Ks[2][64 * 64];
  __shared__ alignas(16) unsigned short Vs[2][64 * 64];
  const int tid = threadIdx.x;
  const int wave = tid >> 6, lane = tid & 63;
  const int l31 = lane & 31, hi = lane >> 5;
  const int bh = blockIdx.y;
  const int q0 = blockIdx.x * 128 + wave * 32;
  const bf16* Qp = Q + (size_t)bh * S_ * DH_;
  const char* Kp = (const char*)(Kb + (size_t)bh * S_ * DH_);
  const char* Vp = (const char*)(Vt + (size_t)bh * DH_ * S_);

  s16x8 qf[4];
#pragma unroll
  for (int dd = 0; dd < 4; dd++)
    qf[dd] = *(const s16x8*)(Qp + (size_t)(q0 + l31) * DH_ + dd * 16 + hi * 8);

  f32x16 acc0, acc1;
#pragma unroll
  for (int r = 0; r < 16; r++) { acc0[r] = 0.f; acc1[r] = 0.f; }
  float lsa = 0.f, lsb = 0.f, lsc = 0.f, lsd = 0.f;

  const int slot16 = (((lane & 7) ^ ((lane >> 3) & 7)) << 4);  // bytes
  const int srow0 = (wave << 4) + (lane >> 3);

#define STAGE(buf, kt)                                                        \
  {                                                                           \
    const char* ksrc = Kp + (size_t)((kt) + srow0) * 128 + slot16;            \
    load_lds16(ksrc, &Ks[buf][(wave << 4) * 64]);                             \
    load_lds16(ksrc + 8 * 128, &Ks[buf][((wave << 4) + 8) * 64]);             \
    const char* vsrc = Vp + (size_t)srow0 * (S_ * 2) + (kt) * 2 + slot16;     \
    load_lds16(vsrc, &Vs[buf][(wave << 4) * 64]);                             \
    load_lds16(vsrc + 8 * (S_ * 2), &Vs[buf][((wave << 4) + 8) * 64]);        \
  }

  f32x16 pA0, pA1, pB0, pB1;
  s16x8 vfA0[4], vfA1[4], vfB0[4], vfB1[4];

#define QKT(buf, q0v, q1v)                                                    \
  {                                                                           \
    _Pragma("unroll") for (int r = 0; r < 16; r++) {                          \
      q0v[r] = 0.f; q1v[r] = 0.f;                                             \
    }                                                                         \
    __builtin_amdgcn_s_setprio(1);                                            \
    _Pragma("unroll") for (int dd = 0; dd < 4; dd++) {                        \
      const int so = (((2 * dd + hi) ^ (lane & 7)) << 3);                     \
      s16x8 kf0 = *(const s16x8*)&Ks[buf][l31 * 64 + so];                     \
      s16x8 kf1 = *(const s16x8*)&Ks[buf][(32 + l31) * 64 + so];              \
      q0v = MFMA32(kf0, qf[dd], q0v);                                         \
      q1v = MFMA32(kf1, qf[dd], q1v);                                         \
    }                                                                         \
    __builtin_amdgcn_s_setprio(0);                                            \
  }

#define LOADV(buf, v0a, v1a)                                                  \
  {                                                                           \
    _Pragma("unroll") for (int d = 0; d < 4; d++) {                           \
      const int so = (((2 * d + hi) ^ (lane & 7)) << 3);                      \
      v0a[d] = *(const s16x8*)&Vs[buf][l31 * 64 + so];                        \
      v1a[d] = *(const s16x8*)&Vs[buf][(32 + l31) * 64 + so];                 \
    }                                                                         \
  }

#define EXPPV(q0v, q1v, v0a, v1a)                                             \
  {                                                                           \
    float ev[32];                                                             \
    _Pragma("unroll") for (int r = 0; r < 16; r++) {                          \
      ev[r] = __expf(fmaxf(q0v[r], 0.f));                                     \
      ev[16 + r] = __expf(fmaxf(q1v[r], 0.f));                                \
      if (r & 1) { lsb += ev[r]; lsd += ev[16 + r]; }                         \
      else       { lsa += ev[r]; lsc += ev[16 + r]; }                         \
    }                                                                         \
    __builtin_amdgcn_s_setprio(1);                                            \
    _Pragma("unroll") for (int d = 0; d < 4; d++) {                           \
      const int eb = ((d >> 1) << 4) + ((d & 1) << 3);                        \
      unsigned A0 = cvtpk_bf16(ev[eb + 0], ev[eb + 1]);                       \
      unsigned A1 = cvtpk_bf16(ev[eb + 2], ev[eb + 3]);                       \
      unsigned B0v = cvtpk_bf16(ev[eb + 4], ev[eb + 5]);                      \
      unsigned B1v = cvtpk_bf16(ev[eb + 6], ev[eb + 7]);                      \
      pl32swap(A0, B0v);                                                      \
      pl32swap(A1, B1v);                                                      \
      union { unsigned w[4]; s16x8 v; } pu;                                   \
      pu.w[0] = A0; pu.w[1] = A1; pu.w[2] = B0v; pu.w[3] = B1v;               \
      acc0 = MFMA32(pu.v, v0a[d], acc0);                                      \
      acc1 = MFMA32(pu.v, v1a[d], acc1);                                      \
    }                                                                         \
    __builtin_amdgcn_s_setprio(0);                                            \
  }

  const int NTL = S_ / 64;  // 32 tiles
  // preamble: tile 0
  STAGE(0, 0);
  __syncthreads();
  STAGE(1, 64);
  QKT(0, pA0, pA1);
  LOADV(0, vfA0, vfA1);
  __syncthreads();  // drains STAGE(1); buf1 ready

  for (int it = 1; it < NTL; it += 2) {
    // tile it (buf1): QK^T + V->regs, overlapped with PV of tile it-1 (regs)
    if (it + 1 < NTL) STAGE(0, (it + 1) * 64);
    QKT(1, pB0, pB1);
    LOADV(1, vfB0, vfB1);
    EXPPV(pA0, pA1, vfA0, vfA1);
    __syncthreads();
    if (it + 1 < NTL) {
      // tile it+1 (buf0), overlapped with PV of tile it
      if (it + 2 < NTL) STAGE(1, (it + 2) * 64);
      QKT(0, pA0, pA1);
      LOADV(0, vfA0, vfA1);
      EXPPV(pB0, pB1, vfB0, vfB1);
      __syncthreads();
    }
  }
  // epilogue: PV of the last tile (NTL-1, held in B set)
  EXPPV(pB0, pB1, vfB0, vfB1);
#undef STAGE
#undef QKT
#undef LOADV
#undef EXPPV

  float lsum = (lsa + lsb) + (lsc + lsd);
  lsum += __shfl_xor(lsum, 32, 64);
  const float rl = 1.f / lsum;
  const int b = bh >> 4, h = bh & 15;
#pragma unroll
  for (int reg = 0; reg < 16; reg++) {
    const int qr = (reg & 3) + ((reg >> 2) << 3) + (hi << 2);
    const float rr = __shfl(rl, qr, 64);
    size_t base = (size_t)(b * S_ + q0 + qr) * D_ + h * DH_ + l31;
    ctx[base] = __float2bfloat16(acc0[reg] * rr);
    ctx[base + 32] = __float2bfloat16(acc1[reg] * rr);
  }
}

// ---------------------------------------------------------------------------
// LayerNorm over last dim (1024); bf16 out (mid) or f32 out (final).
// ---------------------------------------------------------------------------
__device__ __forceinline__ void ln_row(
    const bf16* __restrict__ x, const bf16* __restrict__ g,
    const bf16* __restrict__ b, int row, int tid, float vout[4]) {
  const int lane = tid & 63, wave = tid >> 6;
  const unsigned short* xr = (const unsigned short*)x + (size_t)row * D_;
  ushort4 xv = *(const ushort4*)(xr + tid * 4);
  float v[4];
  v[0] = bfr2f(xv.x); v[1] = bfr2f(xv.y); v[2] = bfr2f(xv.z); v[3] = bfr2f(xv.w);
  float sum = v[0] + v[1] + v[2] + v[3];
  float sq = v[0] * v[0] + v[1] * v[1] + v[2] * v[2] + v[3] * v[3];
  for (int off = 32; off > 0; off >>= 1) {
    sum += __shfl_xor(sum, off, 64);
    sq += __shfl_xor(sq, off, 64);
  }
  __shared__ float red[4][2];
  if (lane == 0) { red[wave][0] = sum; red[wave][1] = sq; }
  __syncthreads();
  sum = red[0][0] + red[1][0] + red[2][0] + red[3][0];
  sq = red[0][1] + red[1][1] + red[2][1] + red[3][1];
  float mu = sum * (1.f / D_);
  float var = sq * (1.f / D_) - mu * mu;
  float rs = rsqrtf(var + 1e-5f);
  ushort4 gv = *(const ushort4*)((const unsigned short*)g + tid * 4);
  ushort4 bv = *(const ushort4*)((const unsigned short*)b + tid * 4);
  vout[0] = (v[0] - mu) * rs * bfr2f(gv.x) + bfr2f(bv.x);
  vout[1] = (v[1] - mu) * rs * bfr2f(gv.y) + bfr2f(bv.y);
  vout[2] = (v[2] - mu) * rs * bfr2f(gv.z) + bfr2f(bv.z);
  vout[3] = (v[3] - mu) * rs * bfr2f(gv.w) + bfr2f(bv.w);
}

__global__ __launch_bounds__(256) void ln_kernel_bf16(
    const bf16* __restrict__ x, const bf16* __restrict__ g,
    const bf16* __restrict__ b, bf16* __restrict__ out) {
  const int row = blockIdx.x, tid = threadIdx.x;
  float v[4];
  ln_row(x, g, b, row, tid, v);
  ushort4 o;
  o.x = f2bfr(v[0]); o.y = f2bfr(v[1]); o.z = f2bfr(v[2]); o.w = f2bfr(v[3]);
  *(ushort4*)((unsigned short*)out + (size_t)row * D_ + tid * 4) = o;
}

__global__ __launch_bounds__(256) void ln_kernel_f32(
    const bf16* __restrict__ x, const bf16* __restrict__ g,
    const bf16* __restrict__ b, float* __restrict__ out) {
  const int row = blockIdx.x, tid = threadIdx.x;
  float v[4];
  ln_row(x, g, b, row, tid, v);
  float4 o = {v[0], v[1], v[2], v[3]};
  *(float4*)(out + (size_t)row * D_ + tid * 4) = o;
}

// ---------------------------------------------------------------------------
// Workspace (70.4 MB peak):
//   0- 8 : Xc -> W1c
//   8-16 : Qb -> z1 -> z2
//   16-24: Kbf -> y
//   24-32: Vb -> W2c
//   32-40: Vt;  40-48: ctx;  32-64: hh (over Vt/ctx/fresh)
//   64-70: Wqkv;  70-: vectors [ln1g|ln1b|ln2g|ln2b|b1|b2]
// ---------------------------------------------------------------------------
extern "C" void kernel_launch(void* const* d_in, const int* in_sizes, int n_in,
                              void* d_out, int out_size, void* d_ws, size_t ws_size,
                              hipStream_t stream) {
  (void)in_sizes; (void)n_in; (void)out_size; (void)ws_size;
  const unsigned* Xs = (const unsigned*)d_in[0];

  char* ws = (char*)d_ws;
  const size_t MB = 1024 * 1024;
  bf16* Xc   = (bf16*)(ws + 0 * MB);
  bf16* W1c  = (bf16*)(ws + 0 * MB);
  bf16* Qb   = (bf16*)(ws + 8 * MB);
  bf16* z1   = (bf16*)(ws + 8 * MB);
  bf16* z2   = (bf16*)(ws + 8 * MB);
  bf16* Kbf  = (bf16*)(ws + 16 * MB);
  bf16* y    = (bf16*)(ws + 16 * MB);
  bf16* Vb   = (bf16*)(ws + 24 * MB);
  bf16* W2c  = (bf16*)(ws + 24 * MB);
  bf16* Vt   = (bf16*)(ws + 32 * MB);
  bf16* hh   = (bf16*)(ws + 32 * MB);
  bf16* ctx  = (bf16*)(ws + 40 * MB);
  bf16* Wqkv = (bf16*)(ws + 64 * MB);
  bf16* vecs = (bf16*)(ws + 70 * MB);
  bf16* ln1g = vecs + 0;
  bf16* ln1b = vecs + 1024;
  bf16* ln2g = vecs + 2048;
  bf16* ln2b = vecs + 3072;
  bf16* b1c  = vecs + 4096;
  bf16* b2c  = vecs + 8192;
  bf16* Woc  = Wqkv + (size_t)2048 * D_;

  dim3 blk(256);
  dim3 blk512(512);
  // Phase 0: conversions.
  convert_kernel<<<dim3(MTOK * D_ / 1024), blk, 0, stream>>>(d_in[0], Xs, Xc, MTOK * D_);
  convert3_kernel<<<dim3(3072), blk, 0, stream>>>(d_in[1], d_in[2], d_in[3], Xs, Wqkv);
  convertvec_kernel<<<dim3(9), blk, 0, stream>>>(d_in[4], d_in[5], d_in[6], d_in[7],
                                                 d_in[9], d_in[11], Xs, vecs);

  // Phase 1: fused QKV + V transpose + attention + out-proj + LN1.
  gemm256<<<dim3(12, 16), blk512, 0, stream>>>(Xc, Wqkv, Qb, nullptr, Kbf, Vb,
                                               MTOK, 3072, D_, 5);
  tpose_v<<<dim3(S_ / 64, B_ * H_), blk, 0, stream>>>(Vb, Vt);
  attn_kernel<<<dim3(S_ / 128, B_ * H_), blk, 0, stream>>>(Qb, Kbf, Vt, ctx);
  gemm64d<<<dim3(16, 32), blk, 0, stream>>>(ctx, Woc, z1, nullptr, Xc,
                                            MTOK, D_, D_, 2);
  ln_kernel_bf16<<<dim3(MTOK), blk, 0, stream>>>(z1, ln1g, ln1b, y);

  // Phase 2: FFN weights into freed slots, FFN, final LN -> f32 out.
  convert_kernel<<<dim3(FF_ * D_ / 1024), blk, 0, stream>>>(d_in[8], Xs, W1c, FF_ * D_);
  convert_kernel<<<dim3(D_ * FF_ / 1024), blk, 0, stream>>>(d_in[10], Xs, W2c, D_ * FF_);
  gemm256<<<dim3(16, 16), blk512, 0, stream>>>(y, W1c, hh, b1c, nullptr, nullptr,
                                               MTOK, FF_, D_, 3);
  gemm64d<<<dim3(16, 32), blk, 0, stream>>>(hh, W2c, z2, b2c, y,
                                            MTOK, D_, FF_, 4);
  ln_kernel_f32<<<dim3(MTOK), blk, 0, stream>>>(z2, ln2g, ln2b, (float*)d_out);
}

// Round 14
// 369.466 us; speedup vs baseline: 1.0425x; 1.0425x over previous
//
#include <hip/hip_runtime.h>
#include <hip/hip_bf16.h>

#define B_ 2
#define S_ 2048
#define D_ 1024
#define H_ 16
#define DH_ 64
#define FF_ 4096
#define MTOK 4096  // B_*S_

using bf16 = __hip_bfloat16;
typedef short s16x8 __attribute__((ext_vector_type(8)));
typedef float f32x4 __attribute__((ext_vector_type(4)));
typedef float f32x16 __attribute__((ext_vector_type(16)));

#define MFMA_BF16(A, Bv, C) __builtin_amdgcn_mfma_f32_16x16x32_bf16(A, Bv, C, 0, 0, 0)
#define MFMA32(A, Bv, C) __builtin_amdgcn_mfma_f32_32x32x16_bf16(A, Bv, C, 0, 0, 0)

__device__ __forceinline__ void load_lds16(const void* g, void* l) {
  __builtin_amdgcn_global_load_lds(
      (const __attribute__((address_space(1))) void*)g,
      (__attribute__((address_space(3))) void*)l, 16, 0, 0);
}

__device__ __forceinline__ float bfr2f(unsigned short u) {
  return __uint_as_float(((unsigned)u) << 16);
}
__device__ __forceinline__ unsigned short f2bfr(float f) {
  __hip_bfloat16 h = __float2bfloat16(f);
  return *(unsigned short*)&h;
}
__device__ __forceinline__ unsigned cvtpk_bf16(float a, float b) {
  unsigned r;
  asm("v_cvt_pk_bf16_f32 %0, %1, %2" : "=v"(r) : "v"(a), "v"(b));
  return r;
}
__device__ __forceinline__ void pl32swap(unsigned& a, unsigned& b) {
  asm("v_permlane32_swap_b32 %0, %1" : "+v"(a), "+v"(b));
}

// ---------------------------------------------------------------------------
// Inputs are float32 (established r5->r6); sniffer kept as insurance.
// ---------------------------------------------------------------------------
__device__ int sniff_is_bf16(const unsigned* Xw) {
  int cnt = 0;
  for (int i = 0; i < 64; i++) {
    unsigned w = Xw[i];
    unsigned short h0 = (unsigned short)(w & 0xFFFF);
    unsigned short h1 = (unsigned short)(w >> 16);
    int e0 = (h0 >> 7) & 0xFF, e1 = (h1 >> 7) & 0xFF;
    if ((e0 >= 100 && e0 <= 140) || (h0 & 0x7FFF) == 0) cnt++;
    if ((e1 >= 100 && e1 <= 140) || (h1 & 0x7FFF) == 0) cnt++;
  }
  return cnt >= 110;
}

__device__ __forceinline__ void conv4(const void* src, bf16* dst, int i, int isbf) {
  ushort4 o;
  if (isbf) {
    o = *(const ushort4*)((const unsigned short*)src + i);
  } else {
    const float4 f = *(const float4*)((const float*)src + i);
    o.x = f2bfr(f.x); o.y = f2bfr(f.y); o.z = f2bfr(f.z); o.w = f2bfr(f.w);
  }
  *(ushort4*)((unsigned short*)dst + i) = o;
}

// ---------------------------------------------------------------------------
// Phase-0 merged conversion (r13: 3 launches -> 1). Block-range dispatch:
//   [0,4096)     : X (4M elems) -> Xc
//   [4096,7168)  : Wq|Wk|Wo (3x1M) -> contiguous Wqkv
//   [7168,7177)  : six small vectors -> [ln1g|ln1b|ln2g|ln2b|b1|b2]
// ---------------------------------------------------------------------------
__global__ __launch_bounds__(256) void convert_all(
    const void* __restrict__ X, const void* __restrict__ s0,
    const void* __restrict__ s1, const void* __restrict__ s2,
    const void* __restrict__ v0, const void* __restrict__ v1,
    const void* __restrict__ v2, const void* __restrict__ v3,
    const void* __restrict__ v4, const void* __restrict__ v5,
    const unsigned* __restrict__ Xs, bf16* __restrict__ Xc,
    bf16* __restrict__ Wqkv, bf16* __restrict__ vecs) {
  __shared__ int isbf;
  if (threadIdx.x == 0) isbf = sniff_is_bf16(Xs);
  __syncthreads();
  const int bid = blockIdx.x;
  if (bid < 4096) {
    int i = (bid * 256 + threadIdx.x) * 4;
    conv4(X, Xc, i, isbf);
  } else if (bid < 7168) {
    int i = ((bid - 4096) * 256 + threadIdx.x) * 4;  // < 3*1048576
    int seg = i >> 20, loc = i & 1048575;
    const void* src = seg == 0 ? s0 : (seg == 1 ? s1 : s2);
    ushort4 o;
    if (isbf) {
      o = *(const ushort4*)((const unsigned short*)src + loc);
    } else {
      const float4 f = *(const float4*)((const float*)src + loc);
      o.x = f2bfr(f.x); o.y = f2bfr(f.y); o.z = f2bfr(f.z); o.w = f2bfr(f.w);
    }
    *(ushort4*)((unsigned short*)Wqkv + i) = o;
  } else {
    int i = ((bid - 7168) * 256 + threadIdx.x) * 4;  // < 9216
    if (i >= 9216) return;
    const void* src; int loc;
    if (i < 4096)      { int s = i >> 10; src = s == 0 ? v0 : s == 1 ? v1 : s == 2 ? v2 : v3; loc = i & 1023; }
    else if (i < 8192) { src = v4; loc = i - 4096; }
    else               { src = v5; loc = i - 8192; }
    ushort4 o;
    if (isbf) {
      o = *(const ushort4*)((const unsigned short*)src + loc);
    } else {
      const float4 f = *(const float4*)((const float*)src + loc);
      o.x = f2bfr(f.x); o.y = f2bfr(f.y); o.z = f2bfr(f.z); o.w = f2bfr(f.w);
    }
    *(ushort4*)((unsigned short*)vecs + i) = o;
  }
}

// ---------------------------------------------------------------------------
// Phase-2 merged conversion (2 launches -> 1): [0,4096): W1, [4096,8192): W2.
// ---------------------------------------------------------------------------
__global__ __launch_bounds__(256) void convert_w12(
    const void* __restrict__ w1, const void* __restrict__ w2,
    const unsigned* __restrict__ Xs, bf16* __restrict__ W1c,
    bf16* __restrict__ W2c) {
  __shared__ int isbf;
  if (threadIdx.x == 0) isbf = sniff_is_bf16(Xs);
  __syncthreads();
  const int bid = blockIdx.x;
  if (bid < 4096) {
    int i = (bid * 256 + threadIdx.x) * 4;
    conv4(w1, W1c, i, isbf);
  } else {
    int i = ((bid - 4096) * 256 + threadIdx.x) * 4;
    conv4(w2, W2c, i, isbf);
  }
}

// ---------------------------------------------------------------------------
// 256x256-tile B^T GEMM, 512 threads (8 waves as 2M x 4N), BK=64, double-
// buffered LDS (128 KiB), 4-phase interleave per K-tile with counted vmcnt
// (T3+T4), LDS XOR-swizzle via pre-swizzled global source (rule #21),
// setprio around MFMA clusters (T5). Epilogue fully unrolled (rule #20).
// modes: 3 = relu(acc + bias)   (FFN1)
//        5 = fused QKV: N=3072; hx=gn>>6: <16 Q, <32 K, else V — head-major.
//            Q outputs are pre-scaled by 0.125 (exact) so attn skips the mul.
// ---------------------------------------------------------------------------
__global__ __launch_bounds__(512, 2) void gemm256(
    const bf16* __restrict__ A, const bf16* __restrict__ Bw,
    bf16* __restrict__ out, const bf16* __restrict__ bias,
    bf16* __restrict__ aux1, bf16* __restrict__ aux2,
    int M, int N, int K, int mode) {
  (void)M;
  __shared__ alignas(16) unsigned short As[4 * 256 * 32];  // [buf][khalf][256][32]
  __shared__ alignas(16) unsigned short Bs[4 * 256 * 32];
  const int tid = threadIdx.x;
  const int wave = tid >> 6, lane = tid & 63;
  const int col = lane & 15, quad = lane >> 4;
  const int wm = (wave >> 2) * 128, wn = (wave & 3) * 64;

  // bijective XCD-chunk swizzle (m204)
  const int gx = gridDim.x;
  const int nwg = gx * gridDim.y;
  const int orig = blockIdx.y * gx + blockIdx.x;
  const int qq = nwg >> 3, rr = nwg & 7;
  const int xcd = orig & 7, lid = orig >> 3;
  const int wg = (xcd < rr ? xcd * (qq + 1) : rr * (qq + 1) + (xcd - rr) * qq) + lid;
  const int m0 = (wg / gx) * 256, n0 = (wg % gx) * 256;

  const int srow = wave * 32 + (lane >> 2);
  const int scol = ((lane & 3) ^ ((lane >> 3) & 3)) * 16;  // bytes, within 64B row
  const char* ga = (const char*)A + (size_t)(m0 + srow) * (K * 2) + scol;
  const char* gb = (const char*)Bw + (size_t)(n0 + srow) * (K * 2) + scol;
  const int ldsw = wave * 1024;  // shorts; + i*512

#define STG_A(i, ks, ob, kb)                                                   \
  load_lds16(ga + (size_t)((i) * 16) * (K * 2) + (size_t)(kb) * 2 + (ks) * 64, \
             (void*)(As + ((((ob) * 2 + (ks)) << 13) + ldsw + (i) * 512)))
#define STG_B(i, ks, ob, kb)                                                   \
  load_lds16(gb + (size_t)((i) * 16) * (K * 2) + (size_t)(kb) * 2 + (ks) * 64, \
             (void*)(Bs + ((((ob) * 2 + (ks)) << 13) + ldsw + (i) * 512)))

  const int swz8 = (quad ^ ((col >> 1) & 3)) * 8;  // shorts
  const int aoff = (wm + col) * 32 + swz8;
  const int boff = (wn + col) * 32 + swz8;

  const f32x4 fz = {0.f, 0.f, 0.f, 0.f};
  f32x4 acc[8][4];
#pragma unroll
  for (int i = 0; i < 8; i++)
#pragma unroll
    for (int j = 0; j < 4; j++) acc[i][j] = fz;

  s16x8 af[4], bfv[4];
#define LDA(ks, buf, mh)                                                       \
  _Pragma("unroll") for (int mt = 0; mt < 4; mt++)                             \
      af[mt] = *(const s16x8*)&As[((((buf) * 2 + (ks)) << 13) + aoff +         \
                                   ((mh) * 4 + mt) * 512)];
#define LDB(ks, buf)                                                           \
  _Pragma("unroll") for (int nt = 0; nt < 4; nt++)                             \
      bfv[nt] =                                                                \
          *(const s16x8*)&Bs[((((buf) * 2 + (ks)) << 13) + boff + nt * 512)];
#define MM(mh)                                                                 \
  __builtin_amdgcn_s_setprio(1);                                               \
  _Pragma("unroll") for (int mt = 0; mt < 4; mt++)                             \
      _Pragma("unroll") for (int nt = 0; nt < 4; nt++)                         \
          acc[(mh) * 4 + mt][nt] =                                             \
              MFMA_BF16(af[mt], bfv[nt], acc[(mh) * 4 + mt][nt]);              \
  __builtin_amdgcn_s_setprio(0);

  const int NT = K >> 6;
  STG_A(0, 0, 0, 0); STG_A(1, 0, 0, 0);
  STG_B(0, 0, 0, 0); STG_B(1, 0, 0, 0);
  STG_A(0, 1, 0, 0); STG_A(1, 1, 0, 0);
  STG_B(0, 1, 0, 0); STG_B(1, 1, 0, 0);

  for (int t = 0; t < NT - 1; ++t) {
    const int buf = t & 1, ob = buf ^ 1;
    const int kb = (t + 1) << 6;
    __builtin_amdgcn_s_barrier();
    STG_A(0, 0, ob, kb); STG_A(1, 0, ob, kb);
    STG_B(0, 0, ob, kb); STG_B(1, 0, ob, kb);
    asm volatile("s_waitcnt vmcnt(6)" ::: "memory");
    __builtin_amdgcn_s_barrier();
    LDA(0, buf, 0); LDB(0, buf);
    MM(0);
    STG_A(0, 1, ob, kb); STG_A(1, 1, ob, kb);
    LDA(0, buf, 1);
    MM(1);
    STG_B(0, 1, ob, kb); STG_B(1, 1, ob, kb);
    asm volatile("s_waitcnt vmcnt(8)" ::: "memory");
    __builtin_amdgcn_s_barrier();
    LDA(1, buf, 0); LDB(1, buf);
    MM(0);
    LDA(1, buf, 1);
    MM(1);
  }
  {  // tail tile
    const int buf = (NT - 1) & 1;
    __builtin_amdgcn_s_barrier();
    asm volatile("s_waitcnt vmcnt(0)" ::: "memory");
    __builtin_amdgcn_s_barrier();
    LDA(0, buf, 0); LDB(0, buf);
    MM(0);
    LDA(0, buf, 1);
    MM(1);
    LDA(1, buf, 0); LDB(1, buf);
    MM(0);
    LDA(1, buf, 1);
    MM(1);
  }
#undef STG_A
#undef STG_B
#undef LDA
#undef LDB
#undef MM

  if (mode == 5) {
#pragma unroll
    for (int mt = 0; mt < 8; mt++)
#pragma unroll
      for (int nt = 0; nt < 4; nt++)
#pragma unroll
        for (int r = 0; r < 4; r++) {
          int gm = m0 + wm + mt * 16 + quad * 4 + r;
          int gn = n0 + wn + nt * 16 + col;
          int b = gm >> 11, s = gm & 2047, hx = gn >> 6, dh = gn & 63;
          bf16* dst = hx < 16 ? out : (hx < 32 ? aux1 : aux2);
          int h = hx & 15;
          float v = acc[mt][nt][r];
          if (hx < 16) v *= 0.125f;  // pre-scale Q (exact; attn skips the mul)
          dst[(((size_t)(b * H_ + h) * S_ + s) << 6) + dh] = __float2bfloat16(v);
        }
  } else {  // mode 3
#pragma unroll
    for (int mt = 0; mt < 8; mt++)
#pragma unroll
      for (int nt = 0; nt < 4; nt++)
#pragma unroll
        for (int r = 0; r < 4; r++) {
          int gm = m0 + wm + mt * 16 + quad * 4 + r;
          int gn = n0 + wn + nt * 16 + col;
          size_t idx = (size_t)gm * N + gn;
          float v = acc[mt][nt][r] + __bfloat162float(bias[gn]);
          out[idx] = __float2bfloat16(fmaxf(v, 0.f));
        }
  }
}

// ---------------------------------------------------------------------------
// 128x64-tile B^T GEMM, 256 threads (4 waves as 2M x 2N -> 64x32 per wave),
// BK=64, double-buffered LDS (48 KiB). Grid 512 = 2 blocks/CU (grid-limited;
// r13 lesson: launch_bounds(256,3) can't add blocks the grid doesn't have).
// Depth-1 counted vmcnt(6); XOR-swizzle via pre-swizzled source (rule #21).
// modes: 2 = acc + res (out-proj);  4 = acc + bias + res (FFN2)
// ---------------------------------------------------------------------------
__global__ __launch_bounds__(256, 3) void gemm64d(
    const bf16* __restrict__ A, const bf16* __restrict__ Bw,
    bf16* __restrict__ out, const bf16* __restrict__ bias,
    const bf16* __restrict__ res, int M, int N, int K, int mode) {
  (void)M;
  __shared__ alignas(16) unsigned short As[2 * 128 * 64];  // [buf][128][64]
  __shared__ alignas(16) unsigned short Bs[2 * 64 * 64];   // [buf][64][64]
  const int tid = threadIdx.x;
  const int wave = tid >> 6, lane = tid & 63;
  const int col = lane & 15, quad = lane >> 4;
  const int wm = (wave >> 1) * 64, wn = (wave & 1) * 32;
  const int sx = col & 7;  // read-side swizzle key

  // bijective XCD swizzle (nwg = 512, divisible by 8)
  const int gx = gridDim.x;  // 16
  const int orig = blockIdx.y * gx + blockIdx.x;
  const int nwg = gx * gridDim.y;
  const int wg = (orig & 7) * (nwg >> 3) + (orig >> 3);
  const int m0 = (wg / gx) * 128, n0 = (wg % gx) * 64;

  const int srow = tid >> 3;            // 0..31
  const int sslot = tid & 7;            // 16B slot
  const size_t K2 = (size_t)K * 2;      // row stride bytes
  const char* ga = (const char*)A + (size_t)(m0 + srow) * K2 +
                   ((sslot ^ (srow & 7)) << 4);
  const char* gb = (const char*)Bw + (size_t)(n0 + srow) * K2 +
                   ((sslot ^ (srow & 7)) << 4);

#define STG64(buf, kb)                                                         \
  {                                                                            \
    const size_t ko = (size_t)(kb) * 2;                                        \
    unsigned short* Ab = As + (buf) * 8192;                                    \
    unsigned short* Bb = Bs + (buf) * 4096;                                    \
    load_lds16(ga + ko,           (void*)(Ab + 0 * 2048 + wave * 512));        \
    load_lds16(ga + ko + 32 * K2, (void*)(Ab + 1 * 2048 + wave * 512));        \
    load_lds16(ga + ko + 64 * K2, (void*)(Ab + 2 * 2048 + wave * 512));        \
    load_lds16(ga + ko + 96 * K2, (void*)(Ab + 3 * 2048 + wave * 512));        \
    load_lds16(gb + ko,           (void*)(Bb + 0 * 2048 + wave * 512));        \
    load_lds16(gb + ko + 32 * K2, (void*)(Bb + 1 * 2048 + wave * 512));        \
  }

  const f32x4 fz = {0.f, 0.f, 0.f, 0.f};
  f32x4 acc[4][2];
#pragma unroll
  for (int i = 0; i < 4; i++)
#pragma unroll
    for (int j = 0; j < 2; j++) acc[i][j] = fz;

#define CMP64(buf)                                                             \
  _Pragma("unroll") for (int kh = 0; kh < 2; kh++) {                           \
    s16x8 Af[4], Bf[2];                                                        \
    const int so = ((kh * 4 + quad) ^ sx) * 8;                                 \
    _Pragma("unroll") for (int mt = 0; mt < 4; mt++)                           \
        Af[mt] = *(const s16x8*)&As[(buf) * 8192 + (wm + mt * 16 + col) * 64 + so]; \
    _Pragma("unroll") for (int nt = 0; nt < 2; nt++)                           \
        Bf[nt] = *(const s16x8*)&Bs[(buf) * 4096 + (wn + nt * 16 + col) * 64 + so]; \
    __builtin_amdgcn_s_setprio(1);                                             \
    _Pragma("unroll") for (int mt = 0; mt < 4; mt++)                           \
        _Pragma("unroll") for (int nt = 0; nt < 2; nt++)                       \
            acc[mt][nt] = MFMA_BF16(Af[mt], Bf[nt], acc[mt][nt]);              \
    __builtin_amdgcn_s_setprio(0);                                             \
  }

  const int NT = K >> 6;
  STG64(0, 0);
  for (int t = 0; t < NT - 1; ++t) {
    const int buf = t & 1;
    STG64(buf ^ 1, (t + 1) << 6);                     // prefetch next tile
    asm volatile("s_waitcnt vmcnt(6)" ::: "memory");  // tile t landed
    __builtin_amdgcn_s_barrier();
    CMP64(buf);
    __builtin_amdgcn_s_barrier();  // all waves done before buf reuse
  }
  {  // tail
    const int buf = (NT - 1) & 1;
    asm volatile("s_waitcnt vmcnt(0)" ::: "memory");
    __builtin_amdgcn_s_barrier();
    CMP64(buf);
  }
#undef STG64
#undef CMP64

  if (mode == 2) {
#pragma unroll
    for (int mt = 0; mt < 4; mt++)
#pragma unroll
      for (int nt = 0; nt < 2; nt++)
#pragma unroll
        for (int r = 0; r < 4; r++) {
          int gm = m0 + wm + mt * 16 + quad * 4 + r;
          int gn = n0 + wn + nt * 16 + col;
          size_t idx = (size_t)gm * N + gn;
          float v = acc[mt][nt][r] + __bfloat162float(res[idx]);
          out[idx] = __float2bfloat16(v);
        }
  } else {  // mode 4
#pragma unroll
    for (int mt = 0; mt < 4; mt++)
#pragma unroll
      for (int nt = 0; nt < 2; nt++)
#pragma unroll
        for (int r = 0; r < 4; r++) {
          int gm = m0 + wm + mt * 16 + quad * 4 + r;
          int gn = n0 + wn + nt * 16 + col;
          size_t idx = (size_t)gm * N + gn;
          float v = acc[mt][nt][r] + __bfloat162float(bias[gn]) +
                    __bfloat162float(res[idx]);
          out[idx] = __float2bfloat16(v);
        }
  }
}

// ---------------------------------------------------------------------------
// V head-major -> Vt [B,H,DH,S] transpose, 64x64 LDS tiles, coalesced I/O.
// ---------------------------------------------------------------------------
__global__ __launch_bounds__(256) void tpose_v(
    const bf16* __restrict__ Vb, bf16* __restrict__ Vt) {
  __shared__ unsigned short Ts[64][72];
  const int tid = threadIdx.x;
  const int bh = blockIdx.y, kt = blockIdx.x;
  const unsigned short* in =
      (const unsigned short*)Vb + (((size_t)bh * S_ + kt * 64) << 6);
  unsigned short* outp =
      (unsigned short*)Vt + ((size_t)bh << 17) + kt * 64;

  const int r = tid >> 2, cc = (tid & 3) * 16;
  s16x8 a = *(const s16x8*)(in + r * 64 + cc);
  s16x8 b = *(const s16x8*)(in + r * 64 + cc + 8);
  for (int j = 0; j < 8; j++) Ts[cc + j][r] = (unsigned short)a[j];
  for (int j = 0; j < 8; j++) Ts[cc + 8 + j][r] = (unsigned short)b[j];
  __syncthreads();
  const int dh = tid >> 2, sc = (tid & 3) * 16;
  s16x8 o0, o1;
  for (int j = 0; j < 8; j++) o0[j] = (short)Ts[dh][sc + j];
  for (int j = 0; j < 8; j++) o1[j] = (short)Ts[dh][sc + 8 + j];
  *(s16x8*)(outp + (size_t)dh * S_ + sc) = o0;
  *(s16x8*)(outp + (size_t)dh * S_ + sc + 8) = o1;
}

// ---------------------------------------------------------------------------
// Flash attention, 32x32x16 MFMA, swapped QK^T (P stays in registers).
// 4 waves x 32 q-rows = 128 q-rows per block; grid (S/128, B*H).
// T15 two-tile pipeline: tile t's QK^T (LDS-gated MFMA) overlaps tile t-1's
// exp+cvt+PV (register-only VALU+MFMA). Two named P/V register sets (A/B,
// rule #20). PV executes tiles in order -> accumulation order bit-identical.
// Q arrives pre-scaled by 0.125 (gemm256 mode-5); __expf fast path (r10).
// ---------------------------------------------------------------------------
__global__ __launch_bounds__(256, 2) void attn_kernel(
    const bf16* __restrict__ Q, const bf16* __restrict__ Kb,
    const bf16* __restrict__ Vt, bf16* __restrict__ ctx) {
  __shared__ alignas(16) unsigned short Ks[2][64 * 64];
  __shared__ alignas(16) unsigned short Vs[2][64 * 64];
  const int tid = threadIdx.x;
  const int wave = tid >> 6, lane = tid & 63;
  const int l31 = lane & 31, hi = lane >> 5;
  const int bh = blockIdx.y;
  const int q0 = blockIdx.x * 128 + wave * 32;
  const bf16* Qp = Q + (size_t)bh * S_ * DH_;
  const char* Kp = (const char*)(Kb + (size_t)bh * S_ * DH_);
  const char* Vp = (const char*)(Vt + (size_t)bh * DH_ * S_);

  s16x8 qf[4];
#pragma unroll
  for (int dd = 0; dd < 4; dd++)
    qf[dd] = *(const s16x8*)(Qp + (size_t)(q0 + l31) * DH_ + dd * 16 + hi * 8);

  f32x16 acc0, acc1;
#pragma unroll
  for (int r = 0; r < 16; r++) { acc0[r] = 0.f; acc1[r] = 0.f; }
  float lsa = 0.f, lsb = 0.f, lsc = 0.f, lsd = 0.f;

  const int slot16 = (((lane & 7) ^ ((lane >> 3) & 7)) << 4);  // bytes
  const int srow0 = (wave << 4) + (lane >> 3);

#define STAGE(buf, kt)                                                        \
  {                                                                           \
    const char* ksrc = Kp + (size_t)((kt) + srow0) * 128 + slot16;            \
    load_lds16(ksrc, &Ks[buf][(wave << 4) * 64]);                             \
    load_lds16(ksrc + 8 * 128, &Ks[buf][((wave << 4) + 8) * 64]);             \
    const char* vsrc = Vp + (size_t)srow0 * (S_ * 2) + (kt) * 2 + slot16;     \
    load_lds16(vsrc, &Vs[buf][(wave << 4) * 64]);                             \
    load_lds16(vsrc + 8 * (S_ * 2), &Vs[buf][((wave << 4) + 8) * 64]);        \
  }

  f32x16 pA0, pA1, pB0, pB1;
  s16x8 vfA0[4], vfA1[4], vfB0[4], vfB1[4];

#define QKT(buf, q0v, q1v)                                                    \
  {                                                                           \
    _Pragma("unroll") for (int r = 0; r < 16; r++) {                          \
      q0v[r] = 0.f; q1v[r] = 0.f;                                             \
    }                                                                         \
    __builtin_amdgcn_s_setprio(1);                                            \
    _Pragma("unroll") for (int dd = 0; dd < 4; dd++) {                        \
      const int so = (((2 * dd + hi) ^ (lane & 7)) << 3);                     \
      s16x8 kf0 = *(const s16x8*)&Ks[buf][l31 * 64 + so];                     \
      s16x8 kf1 = *(const s16x8*)&Ks[buf][(32 + l31) * 64 + so];              \
      q0v = MFMA32(kf0, qf[dd], q0v);                                         \
      q1v = MFMA32(kf1, qf[dd], q1v);                                         \
    }                                                                         \
    __builtin_amdgcn_s_setprio(0);                                            \
  }

#define LOADV(buf, v0a, v1a)                                                  \
  {                                                                           \
    _Pragma("unroll") for (int d = 0; d < 4; d++) {                           \
      const int so = (((2 * d + hi) ^ (lane & 7)) << 3);                      \
      v0a[d] = *(const s16x8*)&Vs[buf][l31 * 64 + so];                        \
      v1a[d] = *(const s16x8*)&Vs[buf][(32 + l31) * 64 + so];                 \
    }                                                                         \
  }

#define EXPPV(q0v, q1v, v0a, v1a)                                             \
  {                                                                           \
    float ev[32];                                                             \
    _Pragma("unroll") for (int r = 0; r < 16; r++) {                          \
      ev[r] = __expf(fmaxf(q0v[r], 0.f));                                     \
      ev[16 + r] = __expf(fmaxf(q1v[r], 0.f));                                \
      if (r & 1) { lsb += ev[r]; lsd += ev[16 + r]; }                         \
      else       { lsa += ev[r]; lsc += ev[16 + r]; }                         \
    }                                                                         \
    __builtin_amdgcn_s_setprio(1);                                            \
    _Pragma("unroll") for (int d = 0; d < 4; d++) {                           \
      const int eb = ((d >> 1) << 4) + ((d & 1) << 3);                        \
      unsigned A0 = cvtpk_bf16(ev[eb + 0], ev[eb + 1]);                       \
      unsigned A1 = cvtpk_bf16(ev[eb + 2], ev[eb + 3]);                       \
      unsigned B0v = cvtpk_bf16(ev[eb + 4], ev[eb + 5]);                      \
      unsigned B1v = cvtpk_bf16(ev[eb + 6], ev[eb + 7]);                      \
      pl32swap(A0, B0v);                                                      \
      pl32swap(A1, B1v);                                                      \
      union { unsigned w[4]; s16x8 v; } pu;                                   \
      pu.w[0] = A0; pu.w[1] = A1; pu.w[2] = B0v; pu.w[3] = B1v;               \
      acc0 = MFMA32(pu.v, v0a[d], acc0);                                      \
      acc1 = MFMA32(pu.v, v1a[d], acc1);                                      \
    }                                                                         \
    __builtin_amdgcn_s_setprio(0);                                            \
  }

  const int NTL = S_ / 64;  // 32 tiles
  STAGE(0, 0);
  __syncthreads();
  STAGE(1, 64);
  QKT(0, pA0, pA1);
  LOADV(0, vfA0, vfA1);
  __syncthreads();  // drains STAGE(1); buf1 ready

  for (int it = 1; it < NTL; it += 2) {
    if (it + 1 < NTL) STAGE(0, (it + 1) * 64);
    QKT(1, pB0, pB1);
    LOADV(1, vfB0, vfB1);
    EXPPV(pA0, pA1, vfA0, vfA1);
    __syncthreads();
    if (it + 1 < NTL) {
      if (it + 2 < NTL) STAGE(1, (it + 2) * 64);
      QKT(0, pA0, pA1);
      LOADV(0, vfA0, vfA1);
      EXPPV(pB0, pB1, vfB0, vfB1);
      __syncthreads();
    }
  }
  EXPPV(pB0, pB1, vfB0, vfB1);
#undef STAGE
#undef QKT
#undef LOADV
#undef EXPPV

  float lsum = (lsa + lsb) + (lsc + lsd);
  lsum += __shfl_xor(lsum, 32, 64);
  const float rl = 1.f / lsum;
  const int b = bh >> 4, h = bh & 15;
#pragma unroll
  for (int reg = 0; reg < 16; reg++) {
    const int qr = (reg & 3) + ((reg >> 2) << 3) + (hi << 2);
    const float rr = __shfl(rl, qr, 64);
    size_t base = (size_t)(b * S_ + q0 + qr) * D_ + h * DH_ + l31;
    ctx[base] = __float2bfloat16(acc0[reg] * rr);
    ctx[base + 32] = __float2bfloat16(acc1[reg] * rr);
  }
}

// ---------------------------------------------------------------------------
// LayerNorm over last dim (1024); bf16 out (mid) or f32 out (final).
// ---------------------------------------------------------------------------
__device__ __forceinline__ void ln_row(
    const bf16* __restrict__ x, const bf16* __restrict__ g,
    const bf16* __restrict__ b, int row, int tid, float vout[4]) {
  const int lane = tid & 63, wave = tid >> 6;
  const unsigned short* xr = (const unsigned short*)x + (size_t)row * D_;
  ushort4 xv = *(const ushort4*)(xr + tid * 4);
  float v[4];
  v[0] = bfr2f(xv.x); v[1] = bfr2f(xv.y); v[2] = bfr2f(xv.z); v[3] = bfr2f(xv.w);
  float sum = v[0] + v[1] + v[2] + v[3];
  float sq = v[0] * v[0] + v[1] * v[1] + v[2] * v[2] + v[3] * v[3];
  for (int off = 32; off > 0; off >>= 1) {
    sum += __shfl_xor(sum, off, 64);
    sq += __shfl_xor(sq, off, 64);
  }
  __shared__ float red[4][2];
  if (lane == 0) { red[wave][0] = sum; red[wave][1] = sq; }
  __syncthreads();
  sum = red[0][0] + red[1][0] + red[2][0] + red[3][0];
  sq = red[0][1] + red[1][1] + red[2][1] + red[3][1];
  float mu = sum * (1.f / D_);
  float var = sq * (1.f / D_) - mu * mu;
  float rs = rsqrtf(var + 1e-5f);
  ushort4 gv = *(const ushort4*)((const unsigned short*)g + tid * 4);
  ushort4 bv = *(const ushort4*)((const unsigned short*)b + tid * 4);
  vout[0] = (v[0] - mu) * rs * bfr2f(gv.x) + bfr2f(bv.x);
  vout[1] = (v[1] - mu) * rs * bfr2f(gv.y) + bfr2f(bv.y);
  vout[2] = (v[2] - mu) * rs * bfr2f(gv.z) + bfr2f(bv.z);
  vout[3] = (v[3] - mu) * rs * bfr2f(gv.w) + bfr2f(bv.w);
}

__global__ __launch_bounds__(256) void ln_kernel_bf16(
    const bf16* __restrict__ x, const bf16* __restrict__ g,
    const bf16* __restrict__ b, bf16* __restrict__ out) {
  const int row = blockIdx.x, tid = threadIdx.x;
  float v[4];
  ln_row(x, g, b, row, tid, v);
  ushort4 o;
  o.x = f2bfr(v[0]); o.y = f2bfr(v[1]); o.z = f2bfr(v[2]); o.w = f2bfr(v[3]);
  *(ushort4*)((unsigned short*)out + (size_t)row * D_ + tid * 4) = o;
}

__global__ __launch_bounds__(256) void ln_kernel_f32(
    const bf16* __restrict__ x, const bf16* __restrict__ g,
    const bf16* __restrict__ b, float* __restrict__ out) {
  const int row = blockIdx.x, tid = threadIdx.x;
  float v[4];
  ln_row(x, g, b, row, tid, v);
  float4 o = {v[0], v[1], v[2], v[3]};
  *(float4*)(out + (size_t)row * D_ + tid * 4) = o;
}

// ---------------------------------------------------------------------------
// Workspace (70.4 MB peak):
//   0- 8 : Xc -> W1c
//   8-16 : Qb -> z1 -> z2
//   16-24: Kbf -> y
//   24-32: Vb -> W2c
//   32-40: Vt;  40-48: ctx;  32-64: hh (over Vt/ctx/fresh)
//   64-70: Wqkv;  70-: vectors [ln1g|ln1b|ln2g|ln2b|b1|b2]
// ---------------------------------------------------------------------------
extern "C" void kernel_launch(void* const* d_in, const int* in_sizes, int n_in,
                              void* d_out, int out_size, void* d_ws, size_t ws_size,
                              hipStream_t stream) {
  (void)in_sizes; (void)n_in; (void)out_size; (void)ws_size;
  const unsigned* Xs = (const unsigned*)d_in[0];

  char* ws = (char*)d_ws;
  const size_t MB = 1024 * 1024;
  bf16* Xc   = (bf16*)(ws + 0 * MB);
  bf16* W1c  = (bf16*)(ws + 0 * MB);
  bf16* Qb   = (bf16*)(ws + 8 * MB);
  bf16* z1   = (bf16*)(ws + 8 * MB);
  bf16* z2   = (bf16*)(ws + 8 * MB);
  bf16* Kbf  = (bf16*)(ws + 16 * MB);
  bf16* y    = (bf16*)(ws + 16 * MB);
  bf16* Vb   = (bf16*)(ws + 24 * MB);
  bf16* W2c  = (bf16*)(ws + 24 * MB);
  bf16* Vt   = (bf16*)(ws + 32 * MB);
  bf16* hh   = (bf16*)(ws + 32 * MB);
  bf16* ctx  = (bf16*)(ws + 40 * MB);
  bf16* Wqkv = (bf16*)(ws + 64 * MB);
  bf16* vecs = (bf16*)(ws + 70 * MB);
  bf16* ln1g = vecs + 0;
  bf16* ln1b = vecs + 1024;
  bf16* ln2g = vecs + 2048;
  bf16* ln2b = vecs + 3072;
  bf16* b1c  = vecs + 4096;
  bf16* b2c  = vecs + 8192;
  bf16* Woc  = Wqkv + (size_t)2048 * D_;

  dim3 blk(256);
  dim3 blk512(512);
  // Phase 0: merged conversions (one launch).
  convert_all<<<dim3(7177), blk, 0, stream>>>(
      d_in[0], d_in[1], d_in[2], d_in[3], d_in[4], d_in[5], d_in[6], d_in[7],
      d_in[9], d_in[11], Xs, Xc, Wqkv, vecs);

  // Phase 1: fused QKV + V transpose + attention + out-proj + LN1.
  gemm256<<<dim3(12, 16), blk512, 0, stream>>>(Xc, Wqkv, Qb, nullptr, Kbf, Vb,
                                               MTOK, 3072, D_, 5);
  tpose_v<<<dim3(S_ / 64, B_ * H_), blk, 0, stream>>>(Vb, Vt);
  attn_kernel<<<dim3(S_ / 128, B_ * H_), blk, 0, stream>>>(Qb, Kbf, Vt, ctx);
  gemm64d<<<dim3(16, 32), blk, 0, stream>>>(ctx, Woc, z1, nullptr, Xc,
                                            MTOK, D_, D_, 2);
  ln_kernel_bf16<<<dim3(MTOK), blk, 0, stream>>>(z1, ln1g, ln1b, y);

  // Phase 2: merged FFN-weight conversion (one launch), FFN, final LN.
  convert_w12<<<dim3(8192), blk, 0, stream>>>(d_in[8], d_in[10], Xs, W1c, W2c);
  gemm256<<<dim3(16, 16), blk512, 0, stream>>>(y, W1c, hh, b1c, nullptr, nullptr,
                                               MTOK, FF_, D_, 3);
  gemm64d<<<dim3(16, 32), blk, 0, stream>>>(hh, W2c, z2, b2c, y,
                                            MTOK, D_, FF_, 4);
  ln_kernel_f32<<<dim3(MTOK), blk, 0, stream>>>(z2, ln2g, ln2b, (float*)d_out);
}

// Round 15
// 364.780 us; speedup vs baseline: 1.0559x; 1.0128x over previous
//
#include <hip/hip_runtime.h>
#include <hip/hip_bf16.h>

#define B_ 2
#define S_ 2048
#define D_ 1024
#define H_ 16
#define DH_ 64
#define FF_ 4096
#define MTOK 4096  // B_*S_

using bf16 = __hip_bfloat16;
typedef short s16x8 __attribute__((ext_vector_type(8)));
typedef float f32x4 __attribute__((ext_vector_type(4)));
typedef float f32x16 __attribute__((ext_vector_type(16)));

#define MFMA_BF16(A, Bv, C) __builtin_amdgcn_mfma_f32_16x16x32_bf16(A, Bv, C, 0, 0, 0)
#define MFMA32(A, Bv, C) __builtin_amdgcn_mfma_f32_32x32x16_bf16(A, Bv, C, 0, 0, 0)

__device__ __forceinline__ void load_lds16(const void* g, void* l) {
  __builtin_amdgcn_global_load_lds(
      (const __attribute__((address_space(1))) void*)g,
      (__attribute__((address_space(3))) void*)l, 16, 0, 0);
}

__device__ __forceinline__ float bfr2f(unsigned short u) {
  return __uint_as_float(((unsigned)u) << 16);
}
__device__ __forceinline__ unsigned short f2bfr(float f) {
  __hip_bfloat16 h = __float2bfloat16(f);
  return *(unsigned short*)&h;
}
__device__ __forceinline__ unsigned cvtpk_bf16(float a, float b) {
  unsigned r;
  asm("v_cvt_pk_bf16_f32 %0, %1, %2" : "=v"(r) : "v"(a), "v"(b));
  return r;
}
__device__ __forceinline__ void pl32swap(unsigned& a, unsigned& b) {
  asm("v_permlane32_swap_b32 %0, %1" : "+v"(a), "+v"(b));
}

// ---------------------------------------------------------------------------
// Inputs are float32 (established r5->r6); sniffer kept as insurance.
// ---------------------------------------------------------------------------
__device__ int sniff_is_bf16(const unsigned* Xw) {
  int cnt = 0;
  for (int i = 0; i < 64; i++) {
    unsigned w = Xw[i];
    unsigned short h0 = (unsigned short)(w & 0xFFFF);
    unsigned short h1 = (unsigned short)(w >> 16);
    int e0 = (h0 >> 7) & 0xFF, e1 = (h1 >> 7) & 0xFF;
    if ((e0 >= 100 && e0 <= 140) || (h0 & 0x7FFF) == 0) cnt++;
    if ((e1 >= 100 && e1 <= 140) || (h1 & 0x7FFF) == 0) cnt++;
  }
  return cnt >= 110;
}

__device__ __forceinline__ void conv4(const void* src, bf16* dst, int i, int isbf) {
  ushort4 o;
  if (isbf) {
    o = *(const ushort4*)((const unsigned short*)src + i);
  } else {
    const float4 f = *(const float4*)((const float*)src + i);
    o.x = f2bfr(f.x); o.y = f2bfr(f.y); o.z = f2bfr(f.z); o.w = f2bfr(f.w);
  }
  *(ushort4*)((unsigned short*)dst + i) = o;
}

// ---------------------------------------------------------------------------
// Phase-0 merged conversion. Block-range dispatch:
//   [0,4096): X -> Xc   [4096,7168): Wq|Wk|Wo -> Wqkv   [7168,7177): vecs
// ---------------------------------------------------------------------------
__global__ __launch_bounds__(256) void convert_all(
    const void* __restrict__ X, const void* __restrict__ s0,
    const void* __restrict__ s1, const void* __restrict__ s2,
    const void* __restrict__ v0, const void* __restrict__ v1,
    const void* __restrict__ v2, const void* __restrict__ v3,
    const void* __restrict__ v4, const void* __restrict__ v5,
    const unsigned* __restrict__ Xs, bf16* __restrict__ Xc,
    bf16* __restrict__ Wqkv, bf16* __restrict__ vecs) {
  __shared__ int isbf;
  if (threadIdx.x == 0) isbf = sniff_is_bf16(Xs);
  __syncthreads();
  const int bid = blockIdx.x;
  if (bid < 4096) {
    int i = (bid * 256 + threadIdx.x) * 4;
    conv4(X, Xc, i, isbf);
  } else if (bid < 7168) {
    int i = ((bid - 4096) * 256 + threadIdx.x) * 4;  // < 3*1048576
    int seg = i >> 20, loc = i & 1048575;
    const void* src = seg == 0 ? s0 : (seg == 1 ? s1 : s2);
    ushort4 o;
    if (isbf) {
      o = *(const ushort4*)((const unsigned short*)src + loc);
    } else {
      const float4 f = *(const float4*)((const float*)src + loc);
      o.x = f2bfr(f.x); o.y = f2bfr(f.y); o.z = f2bfr(f.z); o.w = f2bfr(f.w);
    }
    *(ushort4*)((unsigned short*)Wqkv + i) = o;
  } else {
    int i = ((bid - 7168) * 256 + threadIdx.x) * 4;  // < 9216
    if (i >= 9216) return;
    const void* src; int loc;
    if (i < 4096)      { int s = i >> 10; src = s == 0 ? v0 : s == 1 ? v1 : s == 2 ? v2 : v3; loc = i & 1023; }
    else if (i < 8192) { src = v4; loc = i - 4096; }
    else               { src = v5; loc = i - 8192; }
    ushort4 o;
    if (isbf) {
      o = *(const ushort4*)((const unsigned short*)src + loc);
    } else {
      const float4 f = *(const float4*)((const float*)src + loc);
      o.x = f2bfr(f.x); o.y = f2bfr(f.y); o.z = f2bfr(f.z); o.w = f2bfr(f.w);
    }
    *(ushort4*)((unsigned short*)vecs + i) = o;
  }
}

// ---------------------------------------------------------------------------
// Phase-2 merged conversion: [0,4096): W1, [4096,8192): W2.
// ---------------------------------------------------------------------------
__global__ __launch_bounds__(256) void convert_w12(
    const void* __restrict__ w1, const void* __restrict__ w2,
    const unsigned* __restrict__ Xs, bf16* __restrict__ W1c,
    bf16* __restrict__ W2c) {
  __shared__ int isbf;
  if (threadIdx.x == 0) isbf = sniff_is_bf16(Xs);
  __syncthreads();
  const int bid = blockIdx.x;
  if (bid < 4096) {
    int i = (bid * 256 + threadIdx.x) * 4;
    conv4(w1, W1c, i, isbf);
  } else {
    int i = ((bid - 4096) * 256 + threadIdx.x) * 4;
    conv4(w2, W2c, i, isbf);
  }
}

// ---------------------------------------------------------------------------
// 256x256-tile B^T GEMM, 512 threads (8 waves as 2M x 4N), BK=64, double-
// buffered LDS (128 KiB), 4-phase interleave per K-tile with counted vmcnt
// (T3+T4), LDS XOR-swizzle via pre-swizzled global source (rule #21),
// setprio around MFMA clusters (T5). Epilogue fully unrolled (rule #20).
// modes: 3 = relu(acc + bias)   (FFN1)
//        5 = fused QKV: N=3072; hx=gn>>6: <16 Q, <32 K, else V — head-major.
//            Q outputs are pre-scaled by 0.125 (exact) so attn skips the mul.
// ---------------------------------------------------------------------------
__global__ __launch_bounds__(512, 2) void gemm256(
    const bf16* __restrict__ A, const bf16* __restrict__ Bw,
    bf16* __restrict__ out, const bf16* __restrict__ bias,
    bf16* __restrict__ aux1, bf16* __restrict__ aux2,
    int M, int N, int K, int mode) {
  (void)M;
  __shared__ alignas(16) unsigned short As[4 * 256 * 32];  // [buf][khalf][256][32]
  __shared__ alignas(16) unsigned short Bs[4 * 256 * 32];
  const int tid = threadIdx.x;
  const int wave = tid >> 6, lane = tid & 63;
  const int col = lane & 15, quad = lane >> 4;
  const int wm = (wave >> 2) * 128, wn = (wave & 3) * 64;

  // bijective XCD-chunk swizzle (m204)
  const int gx = gridDim.x;
  const int nwg = gx * gridDim.y;
  const int orig = blockIdx.y * gx + blockIdx.x;
  const int qq = nwg >> 3, rr = nwg & 7;
  const int xcd = orig & 7, lid = orig >> 3;
  const int wg = (xcd < rr ? xcd * (qq + 1) : rr * (qq + 1) + (xcd - rr) * qq) + lid;
  const int m0 = (wg / gx) * 256, n0 = (wg % gx) * 256;

  const int srow = wave * 32 + (lane >> 2);
  const int scol = ((lane & 3) ^ ((lane >> 3) & 3)) * 16;  // bytes, within 64B row
  const char* ga = (const char*)A + (size_t)(m0 + srow) * (K * 2) + scol;
  const char* gb = (const char*)Bw + (size_t)(n0 + srow) * (K * 2) + scol;
  const int ldsw = wave * 1024;  // shorts; + i*512

#define STG_A(i, ks, ob, kb)                                                   \
  load_lds16(ga + (size_t)((i) * 16) * (K * 2) + (size_t)(kb) * 2 + (ks) * 64, \
             (void*)(As + ((((ob) * 2 + (ks)) << 13) + ldsw + (i) * 512)))
#define STG_B(i, ks, ob, kb)                                                   \
  load_lds16(gb + (size_t)((i) * 16) * (K * 2) + (size_t)(kb) * 2 + (ks) * 64, \
             (void*)(Bs + ((((ob) * 2 + (ks)) << 13) + ldsw + (i) * 512)))

  const int swz8 = (quad ^ ((col >> 1) & 3)) * 8;  // shorts
  const int aoff = (wm + col) * 32 + swz8;
  const int boff = (wn + col) * 32 + swz8;

  const f32x4 fz = {0.f, 0.f, 0.f, 0.f};
  f32x4 acc[8][4];
#pragma unroll
  for (int i = 0; i < 8; i++)
#pragma unroll
    for (int j = 0; j < 4; j++) acc[i][j] = fz;

  s16x8 af[4], bfv[4];
#define LDA(ks, buf, mh)                                                       \
  _Pragma("unroll") for (int mt = 0; mt < 4; mt++)                             \
      af[mt] = *(const s16x8*)&As[((((buf) * 2 + (ks)) << 13) + aoff +         \
                                   ((mh) * 4 + mt) * 512)];
#define LDB(ks, buf)                                                           \
  _Pragma("unroll") for (int nt = 0; nt < 4; nt++)                             \
      bfv[nt] =                                                                \
          *(const s16x8*)&Bs[((((buf) * 2 + (ks)) << 13) + boff + nt * 512)];
#define MM(mh)                                                                 \
  __builtin_amdgcn_s_setprio(1);                                               \
  _Pragma("unroll") for (int mt = 0; mt < 4; mt++)                             \
      _Pragma("unroll") for (int nt = 0; nt < 4; nt++)                         \
          acc[(mh) * 4 + mt][nt] =                                             \
              MFMA_BF16(af[mt], bfv[nt], acc[(mh) * 4 + mt][nt]);              \
  __builtin_amdgcn_s_setprio(0);

  const int NT = K >> 6;
  STG_A(0, 0, 0, 0); STG_A(1, 0, 0, 0);
  STG_B(0, 0, 0, 0); STG_B(1, 0, 0, 0);
  STG_A(0, 1, 0, 0); STG_A(1, 1, 0, 0);
  STG_B(0, 1, 0, 0); STG_B(1, 1, 0, 0);

  for (int t = 0; t < NT - 1; ++t) {
    const int buf = t & 1, ob = buf ^ 1;
    const int kb = (t + 1) << 6;
    __builtin_amdgcn_s_barrier();
    STG_A(0, 0, ob, kb); STG_A(1, 0, ob, kb);
    STG_B(0, 0, ob, kb); STG_B(1, 0, ob, kb);
    asm volatile("s_waitcnt vmcnt(6)" ::: "memory");
    __builtin_amdgcn_s_barrier();
    LDA(0, buf, 0); LDB(0, buf);
    MM(0);
    STG_A(0, 1, ob, kb); STG_A(1, 1, ob, kb);
    LDA(0, buf, 1);
    MM(1);
    STG_B(0, 1, ob, kb); STG_B(1, 1, ob, kb);
    asm volatile("s_waitcnt vmcnt(8)" ::: "memory");
    __builtin_amdgcn_s_barrier();
    LDA(1, buf, 0); LDB(1, buf);
    MM(0);
    LDA(1, buf, 1);
    MM(1);
  }
  {  // tail tile
    const int buf = (NT - 1) & 1;
    __builtin_amdgcn_s_barrier();
    asm volatile("s_waitcnt vmcnt(0)" ::: "memory");
    __builtin_amdgcn_s_barrier();
    LDA(0, buf, 0); LDB(0, buf);
    MM(0);
    LDA(0, buf, 1);
    MM(1);
    LDA(1, buf, 0); LDB(1, buf);
    MM(0);
    LDA(1, buf, 1);
    MM(1);
  }
#undef STG_A
#undef STG_B
#undef LDA
#undef LDB
#undef MM

  if (mode == 5) {
#pragma unroll
    for (int mt = 0; mt < 8; mt++)
#pragma unroll
      for (int nt = 0; nt < 4; nt++)
#pragma unroll
        for (int r = 0; r < 4; r++) {
          int gm = m0 + wm + mt * 16 + quad * 4 + r;
          int gn = n0 + wn + nt * 16 + col;
          int b = gm >> 11, s = gm & 2047, hx = gn >> 6, dh = gn & 63;
          bf16* dst = hx < 16 ? out : (hx < 32 ? aux1 : aux2);
          int h = hx & 15;
          float v = acc[mt][nt][r];
          if (hx < 16) v *= 0.125f;  // pre-scale Q (exact; attn skips the mul)
          dst[(((size_t)(b * H_ + h) * S_ + s) << 6) + dh] = __float2bfloat16(v);
        }
  } else {  // mode 3
#pragma unroll
    for (int mt = 0; mt < 8; mt++)
#pragma unroll
      for (int nt = 0; nt < 4; nt++)
#pragma unroll
        for (int r = 0; r < 4; r++) {
          int gm = m0 + wm + mt * 16 + quad * 4 + r;
          int gn = n0 + wn + nt * 16 + col;
          size_t idx = (size_t)gm * N + gn;
          float v = acc[mt][nt][r] + __bfloat162float(bias[gn]);
          out[idx] = __float2bfloat16(fmaxf(v, 0.f));
        }
  }
}

// ---------------------------------------------------------------------------
// 64x64-tile B^T GEMM, 128 threads (2 waves as 2N -> 64x32 per wave), BK=64,
// double-buffered LDS (32 KiB) -> FOUR blocks co-resident per CU (128 KiB).
// r14: per-wave work/LDS-reads/staging totals and K-accumulation order are
// IDENTICAL to the 128x64 version; only the barrier-domain count changes
// (2 -> 4 per CU at constant 8 waves/CU). Clean A/B of "domains vs waves"
// extending the r6->r7 mechanism. Depth-1 counted vmcnt(8); XOR-swizzle via
// pre-swizzled source (rule #21); epilogue fully unrolled (rule #20).
// modes: 2 = acc + res (out-proj);  4 = acc + bias + res (FFN2)
// ---------------------------------------------------------------------------
__global__ __launch_bounds__(128, 2) void gemm64d(
    const bf16* __restrict__ A, const bf16* __restrict__ Bw,
    bf16* __restrict__ out, const bf16* __restrict__ bias,
    const bf16* __restrict__ res, int M, int N, int K, int mode) {
  (void)M;
  __shared__ alignas(16) unsigned short As[2 * 64 * 64];  // [buf][64][64]
  __shared__ alignas(16) unsigned short Bs[2 * 64 * 64];  // [buf][64][64]
  const int tid = threadIdx.x;
  const int wave = tid >> 6, lane = tid & 63;  // wave 0..1
  const int col = lane & 15, quad = lane >> 4;
  const int wn = wave * 32;  // wave's N offset; all waves share M rows 0-63
  const int sx = col & 7;    // read-side swizzle key

  // bijective XCD swizzle (nwg = 1024, divisible by 8)
  const int gx = gridDim.x;  // 16 (n-tiles)
  const int orig = blockIdx.y * gx + blockIdx.x;
  const int nwg = gx * gridDim.y;
  const int wg = (orig & 7) * (nwg >> 3) + (orig >> 3);
  const int m0 = (wg / gx) * 64, n0 = (wg % gx) * 64;

  // staging: per wave-instr 64 lanes x 16B = 1KB = 8 rows x 128B; 2 waves
  // cover 16 rows per line; 4 lines cover the 64-row tile. LDS dest linear
  // (line*1024 + wave*512 shorts = row*64 + lane*8); global source column
  // pre-swizzled: slot_src = slot ^ (row&7), row = wave*8 + (lane>>3)
  // (srow&7 pattern preserved across +16-row lines since 16 = 0 mod 8).
  const int srow = tid >> 3;            // 0..15
  const int sslot = tid & 7;            // 16B slot
  const size_t K2 = (size_t)K * 2;      // row stride bytes
  const char* ga = (const char*)A + (size_t)(m0 + srow) * K2 +
                   ((sslot ^ (srow & 7)) << 4);
  const char* gb = (const char*)Bw + (size_t)(n0 + srow) * K2 +
                   ((sslot ^ (srow & 7)) << 4);

#define STG64(buf, kb)                                                         \
  {                                                                            \
    const size_t ko = (size_t)(kb) * 2;                                        \
    unsigned short* Ab = As + (buf) * 4096;                                    \
    unsigned short* Bb = Bs + (buf) * 4096;                                    \
    load_lds16(ga + ko,           (void*)(Ab + 0 * 1024 + wave * 512));        \
    load_lds16(ga + ko + 16 * K2, (void*)(Ab + 1 * 1024 + wave * 512));        \
    load_lds16(ga + ko + 32 * K2, (void*)(Ab + 2 * 1024 + wave * 512));        \
    load_lds16(ga + ko + 48 * K2, (void*)(Ab + 3 * 1024 + wave * 512));        \
    load_lds16(gb + ko,           (void*)(Bb + 0 * 1024 + wave * 512));        \
    load_lds16(gb + ko + 16 * K2, (void*)(Bb + 1 * 1024 + wave * 512));        \
    load_lds16(gb + ko + 32 * K2, (void*)(Bb + 2 * 1024 + wave * 512));        \
    load_lds16(gb + ko + 48 * K2, (void*)(Bb + 3 * 1024 + wave * 512));        \
  }

  const f32x4 fz = {0.f, 0.f, 0.f, 0.f};
  f32x4 acc[4][2];
#pragma unroll
  for (int i = 0; i < 4; i++)
#pragma unroll
    for (int j = 0; j < 2; j++) acc[i][j] = fz;

#define CMP64(buf)                                                             \
  _Pragma("unroll") for (int kh = 0; kh < 2; kh++) {                           \
    s16x8 Af[4], Bf[2];                                                        \
    const int so = ((kh * 4 + quad) ^ sx) * 8;                                 \
    _Pragma("unroll") for (int mt = 0; mt < 4; mt++)                           \
        Af[mt] = *(const s16x8*)&As[(buf) * 4096 + (mt * 16 + col) * 64 + so]; \
    _Pragma("unroll") for (int nt = 0; nt < 2; nt++)                           \
        Bf[nt] = *(const s16x8*)&Bs[(buf) * 4096 + (wn + nt * 16 + col) * 64 + so]; \
    __builtin_amdgcn_s_setprio(1);                                             \
    _Pragma("unroll") for (int mt = 0; mt < 4; mt++)                           \
        _Pragma("unroll") for (int nt = 0; nt < 2; nt++)                       \
            acc[mt][nt] = MFMA_BF16(Af[mt], Bf[nt], acc[mt][nt]);              \
    __builtin_amdgcn_s_setprio(0);                                             \
  }

  const int NT = K >> 6;
  STG64(0, 0);
  for (int t = 0; t < NT - 1; ++t) {
    const int buf = t & 1;
    STG64(buf ^ 1, (t + 1) << 6);                     // prefetch next tile
    asm volatile("s_waitcnt vmcnt(8)" ::: "memory");  // tile t landed
    __builtin_amdgcn_s_barrier();
    CMP64(buf);
    __builtin_amdgcn_s_barrier();  // all waves done before buf reuse
  }
  {  // tail
    const int buf = (NT - 1) & 1;
    asm volatile("s_waitcnt vmcnt(0)" ::: "memory");
    __builtin_amdgcn_s_barrier();
    CMP64(buf);
  }
#undef STG64
#undef CMP64

  if (mode == 2) {
#pragma unroll
    for (int mt = 0; mt < 4; mt++)
#pragma unroll
      for (int nt = 0; nt < 2; nt++)
#pragma unroll
        for (int r = 0; r < 4; r++) {
          int gm = m0 + mt * 16 + quad * 4 + r;
          int gn = n0 + wn + nt * 16 + col;
          size_t idx = (size_t)gm * N + gn;
          float v = acc[mt][nt][r] + __bfloat162float(res[idx]);
          out[idx] = __float2bfloat16(v);
        }
  } else {  // mode 4
#pragma unroll
    for (int mt = 0; mt < 4; mt++)
#pragma unroll
      for (int nt = 0; nt < 2; nt++)
#pragma unroll
        for (int r = 0; r < 4; r++) {
          int gm = m0 + mt * 16 + quad * 4 + r;
          int gn = n0 + wn + nt * 16 + col;
          size_t idx = (size_t)gm * N + gn;
          float v = acc[mt][nt][r] + __bfloat162float(bias[gn]) +
                    __bfloat162float(res[idx]);
          out[idx] = __float2bfloat16(v);
        }
  }
}

// ---------------------------------------------------------------------------
// V head-major -> Vt [B,H,DH,S] transpose, 64x64 LDS tiles, coalesced I/O.
// ---------------------------------------------------------------------------
__global__ __launch_bounds__(256) void tpose_v(
    const bf16* __restrict__ Vb, bf16* __restrict__ Vt) {
  __shared__ unsigned short Ts[64][72];
  const int tid = threadIdx.x;
  const int bh = blockIdx.y, kt = blockIdx.x;
  const unsigned short* in =
      (const unsigned short*)Vb + (((size_t)bh * S_ + kt * 64) << 6);
  unsigned short* outp =
      (unsigned short*)Vt + ((size_t)bh << 17) + kt * 64;

  const int r = tid >> 2, cc = (tid & 3) * 16;
  s16x8 a = *(const s16x8*)(in + r * 64 + cc);
  s16x8 b = *(const s16x8*)(in + r * 64 + cc + 8);
  for (int j = 0; j < 8; j++) Ts[cc + j][r] = (unsigned short)a[j];
  for (int j = 0; j < 8; j++) Ts[cc + 8 + j][r] = (unsigned short)b[j];
  __syncthreads();
  const int dh = tid >> 2, sc = (tid & 3) * 16;
  s16x8 o0, o1;
  for (int j = 0; j < 8; j++) o0[j] = (short)Ts[dh][sc + j];
  for (int j = 0; j < 8; j++) o1[j] = (short)Ts[dh][sc + 8 + j];
  *(s16x8*)(outp + (size_t)dh * S_ + sc) = o0;
  *(s16x8*)(outp + (size_t)dh * S_ + sc + 8) = o1;
}

// ---------------------------------------------------------------------------
// Flash attention, 32x32x16 MFMA, swapped QK^T (P stays in registers).
// 4 waves x 32 q-rows = 128 q-rows per block; grid (S/128, B*H).
// T15 two-tile pipeline; Q pre-scaled by 0.125; __expf fast path.
// ---------------------------------------------------------------------------
__global__ __launch_bounds__(256, 2) void attn_kernel(
    const bf16* __restrict__ Q, const bf16* __restrict__ Kb,
    const bf16* __restrict__ Vt, bf16* __restrict__ ctx) {
  __shared__ alignas(16) unsigned short Ks[2][64 * 64];
  __shared__ alignas(16) unsigned short Vs[2][64 * 64];
  const int tid = threadIdx.x;
  const int wave = tid >> 6, lane = tid & 63;
  const int l31 = lane & 31, hi = lane >> 5;
  const int bh = blockIdx.y;
  const int q0 = blockIdx.x * 128 + wave * 32;
  const bf16* Qp = Q + (size_t)bh * S_ * DH_;
  const char* Kp = (const char*)(Kb + (size_t)bh * S_ * DH_);
  const char* Vp = (const char*)(Vt + (size_t)bh * DH_ * S_);

  s16x8 qf[4];
#pragma unroll
  for (int dd = 0; dd < 4; dd++)
    qf[dd] = *(const s16x8*)(Qp + (size_t)(q0 + l31) * DH_ + dd * 16 + hi * 8);

  f32x16 acc0, acc1;
#pragma unroll
  for (int r = 0; r < 16; r++) { acc0[r] = 0.f; acc1[r] = 0.f; }
  float lsa = 0.f, lsb = 0.f, lsc = 0.f, lsd = 0.f;

  const int slot16 = (((lane & 7) ^ ((lane >> 3) & 7)) << 4);  // bytes
  const int srow0 = (wave << 4) + (lane >> 3);

#define STAGE(buf, kt)                                                        \
  {                                                                           \
    const char* ksrc = Kp + (size_t)((kt) + srow0) * 128 + slot16;            \
    load_lds16(ksrc, &Ks[buf][(wave << 4) * 64]);                             \
    load_lds16(ksrc + 8 * 128, &Ks[buf][((wave << 4) + 8) * 64]);             \
    const char* vsrc = Vp + (size_t)srow0 * (S_ * 2) + (kt) * 2 + slot16;     \
    load_lds16(vsrc, &Vs[buf][(wave << 4) * 64]);                             \
    load_lds16(vsrc + 8 * (S_ * 2), &Vs[buf][((wave << 4) + 8) * 64]);        \
  }

  f32x16 pA0, pA1, pB0, pB1;
  s16x8 vfA0[4], vfA1[4], vfB0[4], vfB1[4];

#define QKT(buf, q0v, q1v)                                                    \
  {                                                                           \
    _Pragma("unroll") for (int r = 0; r < 16; r++) {                          \
      q0v[r] = 0.f; q1v[r] = 0.f;                                             \
    }                                                                         \
    __builtin_amdgcn_s_setprio(1);                                            \
    _Pragma("unroll") for (int dd = 0; dd < 4; dd++) {                        \
      const int so = (((2 * dd + hi) ^ (lane & 7)) << 3);                     \
      s16x8 kf0 = *(const s16x8*)&Ks[buf][l31 * 64 + so];                     \
      s16x8 kf1 = *(const s16x8*)&Ks[buf][(32 + l31) * 64 + so];              \
      q0v = MFMA32(kf0, qf[dd], q0v);                                         \
      q1v = MFMA32(kf1, qf[dd], q1v);                                         \
    }                                                                         \
    __builtin_amdgcn_s_setprio(0);                                            \
  }

#define LOADV(buf, v0a, v1a)                                                  \
  {                                                                           \
    _Pragma("unroll") for (int d = 0; d < 4; d++) {                           \
      const int so = (((2 * d + hi) ^ (lane & 7)) << 3);                      \
      v0a[d] = *(const s16x8*)&Vs[buf][l31 * 64 + so];                        \
      v1a[d] = *(const s16x8*)&Vs[buf][(32 + l31) * 64 + so];                 \
    }                                                                         \
  }

#define EXPPV(q0v, q1v, v0a, v1a)                                             \
  {                                                                           \
    float ev[32];                                                             \
    _Pragma("unroll") for (int r = 0; r < 16; r++) {                          \
      ev[r] = __expf(fmaxf(q0v[r], 0.f));                                     \
      ev[16 + r] = __expf(fmaxf(q1v[r], 0.f));                                \
      if (r & 1) { lsb += ev[r]; lsd += ev[16 + r]; }                         \
      else       { lsa += ev[r]; lsc += ev[16 + r]; }                         \
    }                                                                         \
    __builtin_amdgcn_s_setprio(1);                                            \
    _Pragma("unroll") for (int d = 0; d < 4; d++) {                           \
      const int eb = ((d >> 1) << 4) + ((d & 1) << 3);                        \
      unsigned A0 = cvtpk_bf16(ev[eb + 0], ev[eb + 1]);                       \
      unsigned A1 = cvtpk_bf16(ev[eb + 2], ev[eb + 3]);                       \
      unsigned B0v = cvtpk_bf16(ev[eb + 4], ev[eb + 5]);                      \
      unsigned B1v = cvtpk_bf16(ev[eb + 6], ev[eb + 7]);                      \
      pl32swap(A0, B0v);                                                      \
      pl32swap(A1, B1v);                                                      \
      union { unsigned w[4]; s16x8 v; } pu;                                   \
      pu.w[0] = A0; pu.w[1] = A1; pu.w[2] = B0v; pu.w[3] = B1v;               \
      acc0 = MFMA32(pu.v, v0a[d], acc0);                                      \
      acc1 = MFMA32(pu.v, v1a[d], acc1);                                      \
    }                                                                         \
    __builtin_amdgcn_s_setprio(0);                                            \
  }

  const int NTL = S_ / 64;  // 32 tiles
  STAGE(0, 0);
  __syncthreads();
  STAGE(1, 64);
  QKT(0, pA0, pA1);
  LOADV(0, vfA0, vfA1);
  __syncthreads();  // drains STAGE(1); buf1 ready

  for (int it = 1; it < NTL; it += 2) {
    if (it + 1 < NTL) STAGE(0, (it + 1) * 64);
    QKT(1, pB0, pB1);
    LOADV(1, vfB0, vfB1);
    EXPPV(pA0, pA1, vfA0, vfA1);
    __syncthreads();
    if (it + 1 < NTL) {
      if (it + 2 < NTL) STAGE(1, (it + 2) * 64);
      QKT(0, pA0, pA1);
      LOADV(0, vfA0, vfA1);
      EXPPV(pB0, pB1, vfB0, vfB1);
      __syncthreads();
    }
  }
  EXPPV(pB0, pB1, vfB0, vfB1);
#undef STAGE
#undef QKT
#undef LOADV
#undef EXPPV

  float lsum = (lsa + lsb) + (lsc + lsd);
  lsum += __shfl_xor(lsum, 32, 64);
  const float rl = 1.f / lsum;
  const int b = bh >> 4, h = bh & 15;
#pragma unroll
  for (int reg = 0; reg < 16; reg++) {
    const int qr = (reg & 3) + ((reg >> 2) << 3) + (hi << 2);
    const float rr = __shfl(rl, qr, 64);
    size_t base = (size_t)(b * S_ + q0 + qr) * D_ + h * DH_ + l31;
    ctx[base] = __float2bfloat16(acc0[reg] * rr);
    ctx[base + 32] = __float2bfloat16(acc1[reg] * rr);
  }
}

// ---------------------------------------------------------------------------
// LayerNorm over last dim (1024); bf16 out (mid) or f32 out (final).
// ---------------------------------------------------------------------------
__device__ __forceinline__ void ln_row(
    const bf16* __restrict__ x, const bf16* __restrict__ g,
    const bf16* __restrict__ b, int row, int tid, float vout[4]) {
  const int lane = tid & 63, wave = tid >> 6;
  const unsigned short* xr = (const unsigned short*)x + (size_t)row * D_;
  ushort4 xv = *(const ushort4*)(xr + tid * 4);
  float v[4];
  v[0] = bfr2f(xv.x); v[1] = bfr2f(xv.y); v[2] = bfr2f(xv.z); v[3] = bfr2f(xv.w);
  float sum = v[0] + v[1] + v[2] + v[3];
  float sq = v[0] * v[0] + v[1] * v[1] + v[2] * v[2] + v[3] * v[3];
  for (int off = 32; off > 0; off >>= 1) {
    sum += __shfl_xor(sum, off, 64);
    sq += __shfl_xor(sq, off, 64);
  }
  __shared__ float red[4][2];
  if (lane == 0) { red[wave][0] = sum; red[wave][1] = sq; }
  __syncthreads();
  sum = red[0][0] + red[1][0] + red[2][0] + red[3][0];
  sq = red[0][1] + red[1][1] + red[2][1] + red[3][1];
  float mu = sum * (1.f / D_);
  float var = sq * (1.f / D_) - mu * mu;
  float rs = rsqrtf(var + 1e-5f);
  ushort4 gv = *(const ushort4*)((const unsigned short*)g + tid * 4);
  ushort4 bv = *(const ushort4*)((const unsigned short*)b + tid * 4);
  vout[0] = (v[0] - mu) * rs * bfr2f(gv.x) + bfr2f(bv.x);
  vout[1] = (v[1] - mu) * rs * bfr2f(gv.y) + bfr2f(bv.y);
  vout[2] = (v[2] - mu) * rs * bfr2f(gv.z) + bfr2f(bv.z);
  vout[3] = (v[3] - mu) * rs * bfr2f(gv.w) + bfr2f(bv.w);
}

__global__ __launch_bounds__(256) void ln_kernel_bf16(
    const bf16* __restrict__ x, const bf16* __restrict__ g,
    const bf16* __restrict__ b, bf16* __restrict__ out) {
  const int row = blockIdx.x, tid = threadIdx.x;
  float v[4];
  ln_row(x, g, b, row, tid, v);
  ushort4 o;
  o.x = f2bfr(v[0]); o.y = f2bfr(v[1]); o.z = f2bfr(v[2]); o.w = f2bfr(v[3]);
  *(ushort4*)((unsigned short*)out + (size_t)row * D_ + tid * 4) = o;
}

__global__ __launch_bounds__(256) void ln_kernel_f32(
    const bf16* __restrict__ x, const bf16* __restrict__ g,
    const bf16* __restrict__ b, float* __restrict__ out) {
  const int row = blockIdx.x, tid = threadIdx.x;
  float v[4];
  ln_row(x, g, b, row, tid, v);
  float4 o = {v[0], v[1], v[2], v[3]};
  *(float4*)(out + (size_t)row * D_ + tid * 4) = o;
}

// ---------------------------------------------------------------------------
// Workspace (70.4 MB peak):
//   0- 8 : Xc -> W1c
//   8-16 : Qb -> z1 -> z2
//   16-24: Kbf -> y
//   24-32: Vb -> W2c
//   32-40: Vt;  40-48: ctx;  32-64: hh (over Vt/ctx/fresh)
//   64-70: Wqkv;  70-: vectors [ln1g|ln1b|ln2g|ln2b|b1|b2]
// ---------------------------------------------------------------------------
extern "C" void kernel_launch(void* const* d_in, const int* in_sizes, int n_in,
                              void* d_out, int out_size, void* d_ws, size_t ws_size,
                              hipStream_t stream) {
  (void)in_sizes; (void)n_in; (void)out_size; (void)ws_size;
  const unsigned* Xs = (const unsigned*)d_in[0];

  char* ws = (char*)d_ws;
  const size_t MB = 1024 * 1024;
  bf16* Xc   = (bf16*)(ws + 0 * MB);
  bf16* W1c  = (bf16*)(ws + 0 * MB);
  bf16* Qb   = (bf16*)(ws + 8 * MB);
  bf16* z1   = (bf16*)(ws + 8 * MB);
  bf16* z2   = (bf16*)(ws + 8 * MB);
  bf16* Kbf  = (bf16*)(ws + 16 * MB);
  bf16* y    = (bf16*)(ws + 16 * MB);
  bf16* Vb   = (bf16*)(ws + 24 * MB);
  bf16* W2c  = (bf16*)(ws + 24 * MB);
  bf16* Vt   = (bf16*)(ws + 32 * MB);
  bf16* hh   = (bf16*)(ws + 32 * MB);
  bf16* ctx  = (bf16*)(ws + 40 * MB);
  bf16* Wqkv = (bf16*)(ws + 64 * MB);
  bf16* vecs = (bf16*)(ws + 70 * MB);
  bf16* ln1g = vecs + 0;
  bf16* ln1b = vecs + 1024;
  bf16* ln2g = vecs + 2048;
  bf16* ln2b = vecs + 3072;
  bf16* b1c  = vecs + 4096;
  bf16* b2c  = vecs + 8192;
  bf16* Woc  = Wqkv + (size_t)2048 * D_;

  dim3 blk(256);
  dim3 blk512(512);
  dim3 blk128(128);
  // Phase 0: merged conversions (one launch).
  convert_all<<<dim3(7177), blk, 0, stream>>>(
      d_in[0], d_in[1], d_in[2], d_in[3], d_in[4], d_in[5], d_in[6], d_in[7],
      d_in[9], d_in[11], Xs, Xc, Wqkv, vecs);

  // Phase 1: fused QKV + V transpose + attention + out-proj + LN1.
  gemm256<<<dim3(12, 16), blk512, 0, stream>>>(Xc, Wqkv, Qb, nullptr, Kbf, Vb,
                                               MTOK, 3072, D_, 5);
  tpose_v<<<dim3(S_ / 64, B_ * H_), blk, 0, stream>>>(Vb, Vt);
  attn_kernel<<<dim3(S_ / 128, B_ * H_), blk, 0, stream>>>(Qb, Kbf, Vt, ctx);
  gemm64d<<<dim3(16, 64), blk128, 0, stream>>>(ctx, Woc, z1, nullptr, Xc,
                                               MTOK, D_, D_, 2);
  ln_kernel_bf16<<<dim3(MTOK), blk, 0, stream>>>(z1, ln1g, ln1b, y);

  // Phase 2: merged FFN-weight conversion (one launch), FFN, final LN.
  convert_w12<<<dim3(8192), blk, 0, stream>>>(d_in[8], d_in[10], Xs, W1c, W2c);
  gemm256<<<dim3(16, 16), blk512, 0, stream>>>(y, W1c, hh, b1c, nullptr, nullptr,
                                               MTOK, FF_, D_, 3);
  gemm64d<<<dim3(16, 64), blk128, 0, stream>>>(hh, W2c, z2, b2c, y,
                                               MTOK, D_, FF_, 4);
  ln_kernel_f32<<<dim3(MTOK), blk, 0, stream>>>(z2, ln2g, ln2b, (float*)d_out);
}